// Round 13
// baseline (815.185 us; speedup 1.0000x reference)
//
#include <hip/hip_runtime.h>
#include <hip/hip_bf16.h>
#include <math.h>

#define S 2048
#define Dm 1024
#define Ee 8
#define Ff 4096

typedef __attribute__((ext_vector_type(8))) short bf16x8;
typedef __attribute__((ext_vector_type(4))) float f32x4;

__device__ __forceinline__ unsigned short f2bf(float f) {
    union { float f; unsigned int u; } c; c.f = f;
    unsigned int r = (c.u + 0x7fffu + ((c.u >> 16) & 1u)) >> 16;
    return (unsigned short)r;
}

__device__ __forceinline__ float bf2f(unsigned short u) {
    union { float f; unsigned int i; } c; c.i = ((unsigned int)u) << 16; return c.f;
}

__device__ __forceinline__ void gload16(const void* g, void* l) {
    __builtin_amdgcn_global_load_lds(
        (const __attribute__((address_space(1))) void*)g,
        (__attribute__((address_space(3))) void*)l, 16, 0, 0);
}

// gelu(x) = 0.5*x*(1+erf(x/sqrt2)); erf via A&S 7.1.26 poly at y=|x|/sqrt2.
__device__ __forceinline__ float gelu_f(float x) {
    float ax = fabsf(x) * 0.70710678118654752f;
    float t = 1.0f / (1.0f + 0.3275911f * ax);
    float p = t * (0.254829592f + t * (-0.284496736f + t * (1.421413741f +
              t * (-1.453152027f + t * 1.061405429f))));
    float er = 1.0f - p * __expf(-ax * ax);
    er = (x < 0.0f) ? -er : er;
    return 0.5f * x * (1.0f + er);
}

// ---------------- LayerNorm 1: writes bf16 ----------------
__global__ __launch_bounds__(256) void ln_kernel(const float* __restrict__ x,
                                                 const float* __restrict__ g,
                                                 const float* __restrict__ b,
                                                 unsigned short* __restrict__ obf) {
    int row = blockIdx.x;
    int tid = threadIdx.x;
    float4 v = ((const float4*)(x + (size_t)row * Dm))[tid];
    float s  = v.x + v.y + v.z + v.w;
    float sq = v.x*v.x + v.y*v.y + v.z*v.z + v.w*v.w;
    #pragma unroll
    for (int off = 1; off < 64; off <<= 1) {
        s  += __shfl_xor(s, off);
        sq += __shfl_xor(sq, off);
    }
    __shared__ float ps[4], pq[4];
    int wave = tid >> 6;
    if ((tid & 63) == 0) { ps[wave] = s; pq[wave] = sq; }
    __syncthreads();
    s  = ps[0] + ps[1] + ps[2] + ps[3];
    sq = pq[0] + pq[1] + pq[2] + pq[3];
    float mean = s * (1.0f / Dm);
    float var  = sq * (1.0f / Dm) - mean * mean;
    float rstd = rsqrtf(var + 1e-5f);
    float4 gv = ((const float4*)g)[tid];
    float4 bv = ((const float4*)b)[tid];
    float4 o;
    o.x = (v.x - mean) * rstd * gv.x + bv.x;
    o.y = (v.y - mean) * rstd * gv.y + bv.y;
    o.z = (v.z - mean) * rstd * gv.z + bv.z;
    o.w = (v.w - mean) * rstd * gv.w + bv.w;
    unsigned short t4[4] = { f2bf(o.x), f2bf(o.y), f2bf(o.z), f2bf(o.w) };
    *(uint2*)(obf + (size_t)row * Dm + tid * 4) = *(uint2*)t4;
}

// ---- Fused: a = x+p0+p1+bo ; out=a ; h2=LN2(a) -> bf16 ; router logits/top2 -> w_rt ----
__global__ __launch_bounds__(256) void ln2_fused(const float* __restrict__ x,
                                                 const float* __restrict__ p0,
                                                 const float* __restrict__ p1,
                                                 const float* __restrict__ bo,
                                                 const float* __restrict__ g,
                                                 const float* __restrict__ b,
                                                 const float* __restrict__ Wr,
                                                 const float* __restrict__ br,
                                                 float* __restrict__ aout,
                                                 unsigned short* __restrict__ h2b,
                                                 float* __restrict__ w_rt) {
    int row = blockIdx.x;
    int tid = threadIdx.x;
    size_t base = (size_t)row * Dm;
    float4 xv = ((const float4*)(x + base))[tid];
    float4 a0 = ((const float4*)(p0 + base))[tid];
    float4 a1 = ((const float4*)(p1 + base))[tid];
    float4 bv0 = ((const float4*)bo)[tid];
    float4 a;
    a.x = xv.x + a0.x + a1.x + bv0.x;
    a.y = xv.y + a0.y + a1.y + bv0.y;
    a.z = xv.z + a0.z + a1.z + bv0.z;
    a.w = xv.w + a0.w + a1.w + bv0.w;
    ((float4*)(aout + base))[tid] = a;
    float s  = a.x + a.y + a.z + a.w;
    float sq = a.x*a.x + a.y*a.y + a.z*a.z + a.w*a.w;
    #pragma unroll
    for (int off = 1; off < 64; off <<= 1) {
        s  += __shfl_xor(s, off);
        sq += __shfl_xor(sq, off);
    }
    __shared__ float ps[4], pq[4];
    int wave = tid >> 6;
    if ((tid & 63) == 0) { ps[wave] = s; pq[wave] = sq; }
    __syncthreads();
    s  = ps[0] + ps[1] + ps[2] + ps[3];
    sq = pq[0] + pq[1] + pq[2] + pq[3];
    float mean = s * (1.0f / Dm);
    float var  = sq * (1.0f / Dm) - mean * mean;
    float rstd = rsqrtf(var + 1e-5f);
    float4 gv = ((const float4*)g)[tid];
    float4 bbv = ((const float4*)b)[tid];
    float4 o;
    o.x = (a.x - mean) * rstd * gv.x + bbv.x;
    o.y = (a.y - mean) * rstd * gv.y + bbv.y;
    o.z = (a.z - mean) * rstd * gv.z + bbv.z;
    o.w = (a.w - mean) * rstd * gv.w + bbv.w;
    unsigned short t4[4] = { f2bf(o.x), f2bf(o.y), f2bf(o.z), f2bf(o.w) };
    *(uint2*)(h2b + base + tid * 4) = *(uint2*)t4;

    // ---- fused router ----
    float lg[8];
    #pragma unroll
    for (int e = 0; e < 8; e++) lg[e] = 0.0f;
    float oc[4] = { o.x, o.y, o.z, o.w };
    #pragma unroll
    for (int c = 0; c < 4; c++) {
        const float4* wr4 = (const float4*)(Wr + (size_t)(tid * 4 + c) * Ee);
        float4 wa = wr4[0], wb = wr4[1];
        lg[0] += oc[c]*wa.x; lg[1] += oc[c]*wa.y; lg[2] += oc[c]*wa.z; lg[3] += oc[c]*wa.w;
        lg[4] += oc[c]*wb.x; lg[5] += oc[c]*wb.y; lg[6] += oc[c]*wb.z; lg[7] += oc[c]*wb.w;
    }
    #pragma unroll
    for (int e = 0; e < 8; e++)
        #pragma unroll
        for (int off = 1; off < 64; off <<= 1) lg[e] += __shfl_xor(lg[e], off);
    __shared__ float wlg[4][8];
    if ((tid & 63) == 0) {
        #pragma unroll
        for (int e = 0; e < 8; e++) wlg[wave][e] = lg[e];
    }
    __syncthreads();
    if (tid == 0) {
        float l8[8];
        #pragma unroll
        for (int e = 0; e < 8; e++) l8[e] = wlg[0][e] + wlg[1][e] + wlg[2][e] + wlg[3][e] + br[e];
        float v1 = -INFINITY, v2 = -INFINITY;
        for (int e = 0; e < 8; e++) {
            float xv2 = l8[e];
            if (xv2 > v1) { v2 = v1; v1 = xv2; }
            else if (xv2 > v2) v2 = xv2;
        }
        float wv[8]; float denom = 0.0f;
        for (int e = 0; e < 8; e++) {
            if (l8[e] >= v2) { wv[e] = __expf(l8[e] - v1); denom += wv[e]; }
            else wv[e] = 0.0f;
        }
        float inv = 1.0f / denom;
        for (int e = 0; e < 8; e++) w_rt[row * Ee + e] = wv[e] * inv;
    }
}

// ---------------- Transpose+convert: src [Kk][Nn] fp32 -> dst [Nn][Kk] bf16 ----------------
__global__ __launch_bounds__(256) void tconv(const float* __restrict__ src,
                                             unsigned short* __restrict__ dst,
                                             int Kk, int Nn) {
    src += (size_t)blockIdx.z * Kk * Nn;
    dst += (size_t)blockIdx.z * Kk * Nn;
    int n0 = blockIdx.x * 64, k0 = blockIdx.y * 64;
    int tid = threadIdx.x;
    __shared__ float t[64][65];
    #pragma unroll
    for (int p = 0; p < 4; p++) {
        int kr = p * 16 + (tid >> 4);
        int nc = (tid & 15) * 4;
        float4 v = *(const float4*)(src + (size_t)(k0 + kr) * Nn + n0 + nc);
        t[kr][nc] = v.x; t[kr][nc+1] = v.y; t[kr][nc+2] = v.z; t[kr][nc+3] = v.w;
    }
    __syncthreads();
    int nr = tid >> 2;
    int kc = (tid & 3) * 16;
    unsigned short o[16];
    #pragma unroll
    for (int j = 0; j < 16; j++) o[j] = f2bf(t[kc + j][nr]);
    *(bf16x8*)(dst + (size_t)(n0 + nr) * Kk + k0 + kc)     = *(bf16x8*)&o[0];
    *(bf16x8*)(dst + (size_t)(n0 + nr) * Kk + k0 + kc + 8) = *(bf16x8*)&o[8];
}

// ---- Merged transpose for the four 1024x1024 attention weights (z picks src/dst) ----
__global__ __launch_bounds__(256) void tconv4(const float* __restrict__ s0,
                                              const float* __restrict__ s1,
                                              const float* __restrict__ s2,
                                              const float* __restrict__ s3,
                                              unsigned short* __restrict__ d0,
                                              unsigned short* __restrict__ d3) {
    int z = blockIdx.z;
    const float* src = (z == 0) ? s0 : (z == 1 ? s1 : (z == 2 ? s2 : s3));
    unsigned short* dst = (z < 3) ? d0 + (size_t)z * 1024 * 1024 : d3;
    int n0 = blockIdx.x * 64, k0 = blockIdx.y * 64;
    int tid = threadIdx.x;
    __shared__ float t[64][65];
    #pragma unroll
    for (int p = 0; p < 4; p++) {
        int kr = p * 16 + (tid >> 4);
        int nc = (tid & 15) * 4;
        float4 v = *(const float4*)(src + (size_t)(k0 + kr) * 1024 + n0 + nc);
        t[kr][nc] = v.x; t[kr][nc+1] = v.y; t[kr][nc+2] = v.z; t[kr][nc+3] = v.w;
    }
    __syncthreads();
    int nr = tid >> 2;
    int kc = (tid & 3) * 16;
    unsigned short o[16];
    #pragma unroll
    for (int j = 0; j < 16; j++) o[j] = f2bf(t[kc + j][nr]);
    *(bf16x8*)(dst + (size_t)(n0 + nr) * 1024 + k0 + kc)     = *(bf16x8*)&o[0];
    *(bf16x8*)(dst + (size_t)(n0 + nr) * 1024 + k0 + kc + 8) = *(bf16x8*)&o[8];
}

// -------- dbuf 128x128 GEMM (QKV / O-proj) --------
// MODE 0: QKV (bias by segment, out bf16 [S][3072])
// MODE 1: OProj (split-K2: z=kc, out fp32 partial [kc][S][Dm], no bias)
template<int MODE>
__global__ __launch_bounds__(256, 2) void gemm_db(const unsigned short* __restrict__ A,
                                                  const unsigned short* __restrict__ Wt,
                                                  const float* __restrict__ bias0,
                                                  const float* __restrict__ bias1,
                                                  const float* __restrict__ bias2,
                                                  void* __restrict__ Cout,
                                                  int M, int N, int K) {
    const int tid = threadIdx.x;
    const int lane = tid & 63;
    const int w = tid >> 6;
    const int lr = lane >> 4, lc = lane & 15;
    const int wr = w >> 1, wc = w & 1;

    int kc = (MODE == 1) ? blockIdx.z : 0;
    const int m0 = blockIdx.y * 128;
    const int n0 = blockIdx.x * 128;
    const int KL   = (MODE == 1) ? 512 : K;
    const int Koff = kc * KL;

    __shared__ __align__(16) unsigned short As[2][128 * 64];
    __shared__ __align__(16) unsigned short Bs[2][128 * 64];

    const int srow = lane >> 3;
    const int csw  = ((lane & 7) ^ srow) * 8;
    const unsigned short* asrc[4];
    const unsigned short* bsrc[4];
    #pragma unroll
    for (int i = 0; i < 4; i++) {
        int rl = w * 32 + i * 8 + srow;
        asrc[i] = A  + (size_t)(m0 + rl) * K + Koff + csw;
        bsrc[i] = Wt + (size_t)(n0 + rl) * K + Koff + csw;
    }

    f32x4 acc[4][4];
    #pragma unroll
    for (int a = 0; a < 4; a++)
        #pragma unroll
        for (int bb = 0; bb < 4; bb++) acc[a][bb] = (f32x4)0.0f;

    auto STAGE = [&](int buf, int kblk) {
        const size_t koff = (size_t)kblk * 64;
        #pragma unroll
        for (int i = 0; i < 4; i++) {
            gload16(asrc[i] + koff, &As[buf][(w * 32 + i * 8) * 64]);
            gload16(bsrc[i] + koff, &Bs[buf][(w * 32 + i * 8) * 64]);
        }
    };

    const int nt = KL / 64;
    STAGE(0, 0);
    for (int t = 0; t < nt; ++t) {
        const int cur = t & 1;
        if (t + 1 < nt) {
            STAGE(cur ^ 1, t + 1);
            asm volatile("s_waitcnt vmcnt(8)" ::: "memory");
        } else {
            asm volatile("s_waitcnt vmcnt(0)" ::: "memory");
        }
        __builtin_amdgcn_s_barrier();
        #pragma unroll
        for (int ks = 0; ks < 2; ks++) {
            const int ck = ((ks * 4 + lr) ^ (lc & 7)) * 8;
            bf16x8 af[4], bfv[4];
            #pragma unroll
            for (int fm = 0; fm < 4; fm++)
                af[fm] = *(const bf16x8*)&As[cur][(wr * 64 + fm * 16 + lc) * 64 + ck];
            #pragma unroll
            for (int fn = 0; fn < 4; fn++)
                bfv[fn] = *(const bf16x8*)&Bs[cur][(wc * 64 + fn * 16 + lc) * 64 + ck];
            #pragma unroll
            for (int fm = 0; fm < 4; fm++)
                #pragma unroll
                for (int fn = 0; fn < 4; fn++)
                    acc[fm][fn] = __builtin_amdgcn_mfma_f32_16x16x32_bf16(af[fm], bfv[fn], acc[fm][fn], 0, 0, 0);
        }
        asm volatile("" ::: "memory");
        __builtin_amdgcn_s_barrier();
    }

    #pragma unroll
    for (int fm = 0; fm < 4; fm++) {
        #pragma unroll
        for (int r = 0; r < 4; r++) {
            int m = m0 + wr * 64 + fm * 16 + lr * 4 + r;
            #pragma unroll
            for (int fn = 0; fn < 4; fn++) {
                int ncol = n0 + wc * 64 + fn * 16 + lc;
                float val = acc[fm][fn][r];
                if constexpr (MODE == 0) {
                    const float* bb = (ncol < 1024) ? bias0 : (ncol < 2048 ? bias1 : bias2);
                    val += bb[ncol & 1023];
                    ((unsigned short*)Cout)[(size_t)m * N + ncol] = f2bf(val);
                } else {
                    ((float*)Cout)[(size_t)kc * M * N + (size_t)m * N + ncol] = val;
                }
            }
        }
    }
}

// -------- MoE GEMM: 128x128, BK=32 (16KB LDS), 6 blocks/CU, compact tile map --------
// Swizzle (BK=32, 4 chunks/row): LDS[row][j] = W[row][j ^ (row&3)]; read chunk = lr ^ (row&3).
// MODE 2: MoE up   (gather rows, GELU, out bf16 compact [slot][Ff])
// MODE 3: MoE down (A compact, split-K4 via blockIdx.z, out bf16 partial eo[kc][4096][Dm])
template<int MODE>
__global__ __launch_bounds__(256, 6) void gemm_moe(const unsigned short* __restrict__ A,
                                                   const unsigned short* __restrict__ Wt,
                                                   const float* __restrict__ bias,
                                                   void* __restrict__ Cout,
                                                   const int* __restrict__ rows,
                                                   const int* __restrict__ counts,
                                                   const int* __restrict__ offs,
                                                   const int* __restrict__ tilemap,
                                                   const int* __restrict__ ntiles,
                                                   int N, int K) {
    const int by = blockIdx.y;
    if (by >= *ntiles) return;
    const int tm = tilemap[by];
    const int e  = tm >> 8;
    const int m0 = (tm & 255) * 128;
    const int kc = (MODE == 3) ? blockIdx.z : 0;

    const int tid = threadIdx.x;
    const int lane = tid & 63;
    const int w = tid >> 6;
    const int lr = lane >> 4, lc = lane & 15;
    const int wr = w >> 1, wc = w & 1;

    const int Mcnt = counts[e];
    const int n0 = blockIdx.x * 128;
    const int KL = (MODE == 3) ? (K >> 2) : K;
    const int Koff = kc * KL;
    const unsigned short* Wz = Wt + (size_t)e * N * K;
    const float* biasz = bias + (size_t)e * N;
    const int zoff = offs[e];

    __shared__ __align__(16) unsigned short As[128 * 32];
    __shared__ __align__(16) unsigned short Bs[128 * 32];

    // staging: one gload16-issue covers 16 rows x 4 chunks; issue q = w*2+i (8 total -> 128 rows)
    const int srow = lane >> 2;                       // 0..15
    const int csw  = ((lane & 3) ^ (srow & 3)) * 8;   // XOR-swizzled source chunk (involution)
    const unsigned short* asrc[2];
    const unsigned short* bsrc[2];
    #pragma unroll
    for (int i = 0; i < 2; i++) {
        int rl = (w * 2 + i) * 16 + srow;
        int ma = m0 + rl;
        int srcRow;
        if constexpr (MODE == 2) srcRow = rows[e * S + (ma < Mcnt ? ma : Mcnt - 1)];
        else                     srcRow = zoff + (ma < Mcnt ? ma : Mcnt - 1);
        asrc[i] = A  + (size_t)srcRow * K + Koff + csw;
        bsrc[i] = Wz + (size_t)(n0 + rl) * K + Koff + csw;
    }

    f32x4 acc[4][4];
    #pragma unroll
    for (int a = 0; a < 4; a++)
        #pragma unroll
        for (int bb = 0; bb < 4; bb++) acc[a][bb] = (f32x4)0.0f;

    const int ckr = (lr ^ (lc & 3)) * 8;   // read chunk position (frag k-slice = lr)

    for (int k0 = 0; k0 < KL; k0 += 32) {
        #pragma unroll
        for (int i = 0; i < 2; i++) {
            gload16(asrc[i] + k0, &As[((w * 2 + i) * 16) * 32]);
            gload16(bsrc[i] + k0, &Bs[((w * 2 + i) * 16) * 32]);
        }
        __syncthreads();
        bf16x8 af[4], bfv[4];
        #pragma unroll
        for (int fm = 0; fm < 4; fm++)
            af[fm] = *(const bf16x8*)&As[(wr * 64 + fm * 16 + lc) * 32 + ckr];
        #pragma unroll
        for (int fn = 0; fn < 4; fn++)
            bfv[fn] = *(const bf16x8*)&Bs[(wc * 64 + fn * 16 + lc) * 32 + ckr];
        #pragma unroll
        for (int fm = 0; fm < 4; fm++)
            #pragma unroll
            for (int fn = 0; fn < 4; fn++)
                acc[fm][fn] = __builtin_amdgcn_mfma_f32_16x16x32_bf16(af[fm], bfv[fn], acc[fm][fn], 0, 0, 0);
        __syncthreads();
    }

    #pragma unroll
    for (int fm = 0; fm < 4; fm++) {
        #pragma unroll
        for (int r = 0; r < 4; r++) {
            int m = m0 + wr * 64 + fm * 16 + lr * 4 + r;
            if (m >= Mcnt) continue;
            #pragma unroll
            for (int fn = 0; fn < 4; fn++) {
                int ncol = n0 + wc * 64 + fn * 16 + lc;
                float val = acc[fm][fn][r];
                if constexpr (MODE == 2) {
                    val += biasz[ncol];
                    ((unsigned short*)Cout)[(size_t)(zoff + m) * N + ncol] = f2bf(gelu_f(val));
                } else {
                    if (kc == 0) val += biasz[ncol];
                    ((unsigned short*)Cout)[(size_t)kc * 4096 * N + (size_t)(zoff + m) * N + ncol] = f2bf(val);
                }
            }
        }
    }
}

// ---------------- MFMA flash attention: balanced pairing, 1 barrier/step, setprio ----------------
__global__ __launch_bounds__(256) void attn_mfma(const unsigned short* __restrict__ qkv,
                                                 unsigned short* __restrict__ ob) {
    int bid = blockIdx.x;
    int qt, h;
    if (bid < 256) { qt = 31 - (bid & 31); h = bid >> 5; }
    else           { qt = bid & 31;        h = 8 + ((bid - 256) >> 5); }
    int tid = threadIdx.x;
    int lane = tid & 63, w = tid >> 6;
    int lr = lane >> 4, lc = lane & 15;

    __shared__ __align__(16) unsigned short Kl[2][64 * 64];
    __shared__ __align__(16) unsigned short Vt[2][64 * 64];
    __shared__ __align__(16) unsigned short Pl[4][16 * 64];

    bf16x8 qf[2];
    int qg_base = qt * 64 + w * 16;
    {
        int qrow = qg_base + lc;
        #pragma unroll
        for (int ks = 0; ks < 2; ks++)
            qf[ks] = *(const bf16x8*)(qkv + (size_t)qrow * 3072 + h * 64 + ks * 32 + lr * 8);
    }

    const int srow = lane >> 3;
    const int scw  = ((lane & 7) ^ srow) * 8;
    const unsigned short* ksrc[2];
    #pragma unroll
    for (int i = 0; i < 2; i++)
        ksrc[i] = qkv + (size_t)(w * 16 + i * 8 + srow) * 3072 + h * 64 + 1024 + scw;
    int vrow[2], vcg[2];
    const unsigned short* vsrc[2];
    #pragma unroll
    for (int i = 0; i < 2; i++) {
        int u = tid + i * 256;
        vrow[i] = u >> 3; vcg[i] = (u & 7) * 8;
        vsrc[i] = qkv + (size_t)vrow[i] * 3072 + h * 64 + 2048 + vcg[i];
    }

    f32x4 oacc[4];
    #pragma unroll
    for (int fd = 0; fd < 4; fd++) oacc[fd] = (f32x4)0.0f;
    float mrun[4], lrun[4];
    #pragma unroll
    for (int r = 0; r < 4; r++) { mrun[r] = -INFINITY; lrun[r] = 0.0f; }

    bf16x8 vreg[2];
    vreg[0] = *(const bf16x8*)(vsrc[0]);
    vreg[1] = *(const bf16x8*)(vsrc[1]);
    gload16(ksrc[0], &Kl[0][(w * 16 + 0) * 64]);
    gload16(ksrc[1], &Kl[0][(w * 16 + 8) * 64]);
    #pragma unroll
    for (int i = 0; i < 2; i++)
        #pragma unroll
        for (int j = 0; j < 8; j++) {
            int d = vcg[i] + j;
            int ch = ((vrow[i] >> 3) ^ (d & 7) ^ (d >> 3)) & 7;
            Vt[0][d * 64 + ch * 8 + (vrow[i] & 7)] = (unsigned short)vreg[i][j];
        }
    __syncthreads();

    for (int kt = 0; kt <= qt; kt++) {
        const int cur = kt & 1;
        if (kt < qt) {
            size_t off = (size_t)(kt + 1) * 64 * 3072;
            vreg[0] = *(const bf16x8*)(vsrc[0] + off);
            vreg[1] = *(const bf16x8*)(vsrc[1] + off);
            gload16(ksrc[0] + off, &Kl[cur ^ 1][(w * 16 + 0) * 64]);
            gload16(ksrc[1] + off, &Kl[cur ^ 1][(w * 16 + 8) * 64]);
        }

        f32x4 sc[4];
        #pragma unroll
        for (int fn = 0; fn < 4; fn++) sc[fn] = (f32x4)0.0f;
        __builtin_amdgcn_s_setprio(1);
        #pragma unroll
        for (int fn = 0; fn < 4; fn++)
            #pragma unroll
            for (int ks = 0; ks < 2; ks++) {
                bf16x8 kf = *(const bf16x8*)&Kl[cur][(fn * 16 + lc) * 64 + ((ks * 4 + lr) ^ (lc & 7)) * 8];
                sc[fn] = __builtin_amdgcn_mfma_f32_16x16x32_bf16(qf[ks], kf, sc[fn], 0, 0, 0);
            }
        __builtin_amdgcn_s_setprio(0);

        float st[4][4];
        float mloc[4];
        #pragma unroll
        for (int r = 0; r < 4; r++) mloc[r] = -INFINITY;
        #pragma unroll
        for (int fn = 0; fn < 4; fn++)
            #pragma unroll
            for (int r = 0; r < 4; r++) {
                float sv = sc[fn][r] * 0.125f;
                if (kt == qt) {
                    int kvg = kt * 64 + fn * 16 + lc;
                    int qg  = qg_base + lr * 4 + r;
                    if (kvg > qg) sv = -INFINITY;
                }
                st[fn][r] = sv;
                mloc[r] = fmaxf(mloc[r], sv);
            }
        #pragma unroll
        for (int r = 0; r < 4; r++) {
            mloc[r] = fmaxf(mloc[r], __shfl_xor(mloc[r], 1));
            mloc[r] = fmaxf(mloc[r], __shfl_xor(mloc[r], 2));
            mloc[r] = fmaxf(mloc[r], __shfl_xor(mloc[r], 4));
            mloc[r] = fmaxf(mloc[r], __shfl_xor(mloc[r], 8));
        }
        float fsc[4], lpart[4];
        #pragma unroll
        for (int r = 0; r < 4; r++) {
            float mnew = fmaxf(mrun[r], mloc[r]);
            fsc[r] = __expf(mrun[r] - mnew);
            mrun[r] = mnew;
            lpart[r] = 0.0f;
        }
        float pv[4][4];
        #pragma unroll
        for (int fn = 0; fn < 4; fn++)
            #pragma unroll
            for (int r = 0; r < 4; r++) {
                pv[fn][r] = __expf(st[fn][r] - mrun[r]);
                lpart[r] += pv[fn][r];
            }
        #pragma unroll
        for (int r = 0; r < 4; r++) {
            lpart[r] += __shfl_xor(lpart[r], 1);
            lpart[r] += __shfl_xor(lpart[r], 2);
            lpart[r] += __shfl_xor(lpart[r], 4);
            lpart[r] += __shfl_xor(lpart[r], 8);
            lrun[r] = lrun[r] * fsc[r] + lpart[r];
        }
        #pragma unroll
        for (int fn = 0; fn < 4; fn++)
            #pragma unroll
            for (int r = 0; r < 4; r++) {
                int q = lr * 4 + r;
                int kvc = fn * 16 + lc;
                int ch = ((kvc >> 3) ^ (q & 7) ^ (q >> 3)) & 7;
                Pl[w][q * 64 + ch * 8 + (kvc & 7)] = f2bf(pv[fn][r]);
            }
        #pragma unroll
        for (int fd = 0; fd < 4; fd++)
            #pragma unroll
            for (int r = 0; r < 4; r++) oacc[fd][r] *= fsc[r];

        if (kt < qt) {
            #pragma unroll
            for (int i = 0; i < 2; i++)
                #pragma unroll
                for (int j = 0; j < 8; j++) {
                    int d = vcg[i] + j;
                    int ch = ((vrow[i] >> 3) ^ (d & 7) ^ (d >> 3)) & 7;
                    Vt[cur ^ 1][d * 64 + ch * 8 + (vrow[i] & 7)] = (unsigned short)vreg[i][j];
                }
        }

        __builtin_amdgcn_s_setprio(1);
        #pragma unroll
        for (int ks = 0; ks < 2; ks++) {
            int chp = ((ks * 4 + lr) ^ (lc & 7) ^ (lc >> 3)) & 7;
            bf16x8 pa = *(const bf16x8*)&Pl[w][lc * 64 + chp * 8];
            #pragma unroll
            for (int fd = 0; fd < 4; fd++) {
                int d = fd * 16 + lc;
                int chv = ((ks * 4 + lr) ^ (d & 7) ^ (d >> 3)) & 7;
                bf16x8 vb = *(const bf16x8*)&Vt[cur][d * 64 + chv * 8];
                oacc[fd] = __builtin_amdgcn_mfma_f32_16x16x32_bf16(pa, vb, oacc[fd], 0, 0, 0);
            }
        }
        __builtin_amdgcn_s_setprio(0);
        __syncthreads();
    }
    #pragma unroll
    for (int fd = 0; fd < 4; fd++)
        #pragma unroll
        for (int r = 0; r < 4; r++) {
            float val = oacc[fd][r] / lrun[r];
            ob[(size_t)(qg_base + lr * 4 + r) * 1024 + h * 64 + fd * 16 + lc] = f2bf(val);
        }
}

// ------- Token lists + offsets + token->slot map + compact tile map (single block) -------
__global__ __launch_bounds__(256) void listbuild_kernel(const float* __restrict__ w_rt,
                                                        int* __restrict__ rows,
                                                        int* __restrict__ counts,
                                                        int* __restrict__ offs,
                                                        int* __restrict__ tok2slot,
                                                        float* __restrict__ tokw,
                                                        int* __restrict__ tilemap,
                                                        int* __restrict__ ntiles) {
    int tid = threadIdx.x;
    __shared__ int sc[256];
    __shared__ int runoff_s;
    __shared__ int scounts[8];
    int ncnt[8];
    #pragma unroll
    for (int j = 0; j < 8; j++) ncnt[j] = 0;
    if (tid == 0) runoff_s = 0;
    __syncthreads();
    for (int e = 0; e < Ee; e++) {
        int t0 = tid * 8;
        int sel = 0, flags = 0;
        #pragma unroll
        for (int j = 0; j < 8; j++)
            if (w_rt[(size_t)(t0 + j) * Ee + e] > 0.0f) { flags |= 1 << j; sel++; }
        sc[tid] = sel;
        __syncthreads();
        for (int off = 1; off < 256; off <<= 1) {
            int add = (tid >= off) ? sc[tid - off] : 0;
            __syncthreads();
            sc[tid] += add;
            __syncthreads();
        }
        int base = runoff_s;
        int pos = sc[tid] - sel;
        #pragma unroll
        for (int j = 0; j < 8; j++) {
            if (flags & (1 << j)) {
                rows[e * S + pos] = t0 + j;
                int c = ncnt[j];
                if (c < 2) {
                    tok2slot[(t0 + j) * 2 + c] = base + pos;
                    tokw[(t0 + j) * 2 + c] = w_rt[(size_t)(t0 + j) * Ee + e];
                    ncnt[j] = c + 1;
                }
                pos++;
            }
        }
        __syncthreads();
        if (tid == 0) {
            offs[e] = base;
            counts[e] = sc[255];
            scounts[e] = sc[255];
            runoff_s = base + sc[255];
        }
        __syncthreads();
    }
    if (tid == 0) {
        int t = 0;
        for (int e = 0; e < Ee; e++) {
            int nmt = (scounts[e] + 127) >> 7;
            for (int mt = 0; mt < nmt; mt++) tilemap[t++] = (e << 8) | mt;
        }
        *ntiles = t;
        for (int j = t; j < 40; j++) tilemap[j] = 0;
    }
}

// -------- Combine: out[t] += w0*sum_p eo[p][s0] + w1*sum_p eo[p][s1]  (4 bf16 partials) --------
__global__ __launch_bounds__(256) void combine_kernel(float* __restrict__ out,
                                                      const unsigned short* __restrict__ eo,
                                                      const int* __restrict__ tok2slot,
                                                      const float* __restrict__ tokw) {
    int t = blockIdx.x, d = threadIdx.x;
    int s0 = tok2slot[t * 2], s1 = tok2slot[t * 2 + 1];
    float w0 = tokw[t * 2], w1 = tokw[t * 2 + 1];
    float4 o = ((const float4*)(out + (size_t)t * Dm))[d];
    float a[4] = {0,0,0,0}, b[4] = {0,0,0,0};
    #pragma unroll
    for (int p = 0; p < 4; p++) {
        const unsigned short* ep = eo + (size_t)p * 4096 * Dm;
        uint2 ra = *(const uint2*)(ep + (size_t)s0 * Dm + d * 4);
        uint2 rb = *(const uint2*)(ep + (size_t)s1 * Dm + d * 4);
        const unsigned short* pa16 = (const unsigned short*)&ra;
        const unsigned short* pb16 = (const unsigned short*)&rb;
        #pragma unroll
        for (int j = 0; j < 4; j++) { a[j] += bf2f(pa16[j]); b[j] += bf2f(pb16[j]); }
    }
    o.x += w0 * a[0] + w1 * b[0];
    o.y += w0 * a[1] + w1 * b[1];
    o.z += w0 * a[2] + w1 * b[2];
    o.w += w0 * a[3] + w1 * b[3];
    ((float4*)(out + (size_t)t * Dm))[d] = o;
}

extern "C" void kernel_launch(void* const* d_in, const int* in_sizes, int n_in,
                              void* d_out, int out_size, void* d_ws, size_t ws_size,
                              hipStream_t stream) {
    const float* x    = (const float*)d_in[0];
    const float* ln1g = (const float*)d_in[1];
    const float* ln1b = (const float*)d_in[2];
    const float* ln2g = (const float*)d_in[3];
    const float* ln2b = (const float*)d_in[4];
    const float* Wq   = (const float*)d_in[5];
    const float* bq   = (const float*)d_in[6];
    const float* Wk   = (const float*)d_in[7];
    const float* bk   = (const float*)d_in[8];
    const float* Wv   = (const float*)d_in[9];
    const float* bv   = (const float*)d_in[10];
    const float* Wo   = (const float*)d_in[11];
    const float* bo   = (const float*)d_in[12];
    const float* Wr   = (const float*)d_in[13];
    const float* br   = (const float*)d_in[14];
    const float* ew1  = (const float*)d_in[15];
    const float* eb1  = (const float*)d_in[16];
    const float* ew2  = (const float*)d_in[17];
    const float* eb2  = (const float*)d_in[18];
    float* out = (float*)d_out;

    char* wsb = (char*)d_ws;
    const size_t MB = 1 << 20;
    unsigned short* ew1T = (unsigned short*)(wsb);               //   0: 64 MB (dead after up)
    unsigned short* eo   = (unsigned short*)(wsb);               //   0: 32 MB = 4 bf16 partials (overlays ew1T)
    unsigned short* ew2T = (unsigned short*)(wsb + 64*MB);       //  64: 64 MB
    unsigned short* mid  = (unsigned short*)(wsb + 128*MB);      // 128: 32 MB [4096][Ff] bf16
    unsigned short* qkvT = (unsigned short*)(wsb + 160*MB);      // 160:  6 MB
    unsigned short* WoT  = (unsigned short*)(wsb + 166*MB);      // 166:  2 MB
    unsigned short* h_bf = (unsigned short*)(wsb + 168*MB);      // 168:  4 MB (dead after QKV)
    unsigned short* qkv  = (unsigned short*)(wsb + 172*MB);      // 172: 12 MB (dead after attn)
    float*          p01  = (float*)         (wsb + 168*MB);      // 168: 16 MB (overlays h_bf+qkv)
    unsigned short* ob   = (unsigned short*)(wsb + 184*MB);      // 184:  4 MB
    unsigned short* h2b  = (unsigned short*)(wsb + 196*MB);      // 196:  4 MB
    float*          w_rt = (float*)         (wsb + 200*MB);
    int*            rows = (int*)           (wsb + 200*MB + 65536);
    int*            counts   = rows + Ee * S;
    int*            offs     = counts + Ee;
    int*            tok2slot = offs + Ee;
    float*          tokw     = (float*)(tok2slot + 2 * S);
    int*            tilemap  = (int*)(tokw + 2 * S);
    int*            ntiles   = tilemap + 40;

    // ---- one-shot weight transpose+convert to bf16 [N][K] ----
    tconv4<<<dim3(16, 16, 4), 256, 0, stream>>>(Wq, Wk, Wv, Wo, qkvT, WoT);
    tconv<<<dim3(64, 16, 8), 256, 0, stream>>>(ew1, ew1T, Dm, Ff);
    tconv<<<dim3(16, 64, 8), 256, 0, stream>>>(ew2, ew2T, Ff, Dm);

    ln_kernel<<<S, 256, 0, stream>>>(x, ln1g, ln1b, h_bf);

    gemm_db<0><<<dim3(24, 16), 256, 0, stream>>>(h_bf, qkvT, bq, bk, bv,
        qkv, S, 3072, Dm);

    attn_mfma<<<dim3(512, 1), 256, 0, stream>>>(qkv, ob);

    gemm_db<1><<<dim3(8, 16, 2), 256, 0, stream>>>(ob, WoT, nullptr, nullptr, nullptr,
        p01, S, Dm, Dm);

    ln2_fused<<<S, 256, 0, stream>>>(x, p01, p01 + (size_t)S * Dm, bo, ln2g, ln2b,
                                     Wr, br, out, h2b, w_rt);
    listbuild_kernel<<<1, 256, 0, stream>>>(w_rt, rows, counts, offs, tok2slot, tokw,
                                            tilemap, ntiles);

    // MoE up: BK=32, 6 blocks/CU — grid 32n x 40mt
    gemm_moe<2><<<dim3(32, 40, 1), 256, 0, stream>>>(h2b, ew1T, eb1,
        mid, rows, counts, offs, tilemap, ntiles, Ff, Dm);

    // MoE down: split-K4, grid 8n x 40mt x 4kc
    gemm_moe<3><<<dim3(8, 40, 4), 256, 0, stream>>>(mid, ew2T, eb2,
        eo, rows, counts, offs, tilemap, ntiles, Dm, Ff);

    combine_kernel<<<S, 256, 0, stream>>>(out, eo, tok2slot, tokw);
}

// Round 14
// 660.756 us; speedup vs baseline: 1.2337x; 1.2337x over previous
//
#include <hip/hip_runtime.h>
#include <hip/hip_bf16.h>
#include <math.h>

#define S 2048
#define Dm 1024
#define Ee 8
#define Ff 4096

typedef __attribute__((ext_vector_type(8))) short bf16x8;
typedef __attribute__((ext_vector_type(4))) float f32x4;

__device__ __forceinline__ unsigned short f2bf(float f) {
    union { float f; unsigned int u; } c; c.f = f;
    unsigned int r = (c.u + 0x7fffu + ((c.u >> 16) & 1u)) >> 16;
    return (unsigned short)r;
}

__device__ __forceinline__ float bf2f(unsigned short u) {
    union { float f; unsigned int i; } c; c.i = ((unsigned int)u) << 16; return c.f;
}

__device__ __forceinline__ void gload16(const void* g, void* l) {
    __builtin_amdgcn_global_load_lds(
        (const __attribute__((address_space(1))) void*)g,
        (__attribute__((address_space(3))) void*)l, 16, 0, 0);
}

// gelu(x) = 0.5*x*(1+erf(x/sqrt2)); erf via A&S 7.1.26 poly at y=|x|/sqrt2.
__device__ __forceinline__ float gelu_f(float x) {
    float ax = fabsf(x) * 0.70710678118654752f;
    float t = 1.0f / (1.0f + 0.3275911f * ax);
    float p = t * (0.254829592f + t * (-0.284496736f + t * (1.421413741f +
              t * (-1.453152027f + t * 1.061405429f))));
    float er = 1.0f - p * __expf(-ax * ax);
    er = (x < 0.0f) ? -er : er;
    return 0.5f * x * (1.0f + er);
}

// ---------------- LayerNorm 1: writes bf16 ----------------
__global__ __launch_bounds__(256) void ln_kernel(const float* __restrict__ x,
                                                 const float* __restrict__ g,
                                                 const float* __restrict__ b,
                                                 unsigned short* __restrict__ obf) {
    int row = blockIdx.x;
    int tid = threadIdx.x;
    float4 v = ((const float4*)(x + (size_t)row * Dm))[tid];
    float s  = v.x + v.y + v.z + v.w;
    float sq = v.x*v.x + v.y*v.y + v.z*v.z + v.w*v.w;
    #pragma unroll
    for (int off = 1; off < 64; off <<= 1) {
        s  += __shfl_xor(s, off);
        sq += __shfl_xor(sq, off);
    }
    __shared__ float ps[4], pq[4];
    int wave = tid >> 6;
    if ((tid & 63) == 0) { ps[wave] = s; pq[wave] = sq; }
    __syncthreads();
    s  = ps[0] + ps[1] + ps[2] + ps[3];
    sq = pq[0] + pq[1] + pq[2] + pq[3];
    float mean = s * (1.0f / Dm);
    float var  = sq * (1.0f / Dm) - mean * mean;
    float rstd = rsqrtf(var + 1e-5f);
    float4 gv = ((const float4*)g)[tid];
    float4 bv = ((const float4*)b)[tid];
    float4 o;
    o.x = (v.x - mean) * rstd * gv.x + bv.x;
    o.y = (v.y - mean) * rstd * gv.y + bv.y;
    o.z = (v.z - mean) * rstd * gv.z + bv.z;
    o.w = (v.w - mean) * rstd * gv.w + bv.w;
    unsigned short t4[4] = { f2bf(o.x), f2bf(o.y), f2bf(o.z), f2bf(o.w) };
    *(uint2*)(obf + (size_t)row * Dm + tid * 4) = *(uint2*)t4;
}

// ---- Fused: a = x+p0+p1+bo ; out=a ; h2=LN2(a) -> bf16 ; router logits/top2 -> w_rt ----
__global__ __launch_bounds__(256) void ln2_fused(const float* __restrict__ x,
                                                 const float* __restrict__ p0,
                                                 const float* __restrict__ p1,
                                                 const float* __restrict__ bo,
                                                 const float* __restrict__ g,
                                                 const float* __restrict__ b,
                                                 const float* __restrict__ Wr,
                                                 const float* __restrict__ br,
                                                 float* __restrict__ aout,
                                                 unsigned short* __restrict__ h2b,
                                                 float* __restrict__ w_rt) {
    int row = blockIdx.x;
    int tid = threadIdx.x;
    size_t base = (size_t)row * Dm;
    float4 xv = ((const float4*)(x + base))[tid];
    float4 a0 = ((const float4*)(p0 + base))[tid];
    float4 a1 = ((const float4*)(p1 + base))[tid];
    float4 bv0 = ((const float4*)bo)[tid];
    float4 a;
    a.x = xv.x + a0.x + a1.x + bv0.x;
    a.y = xv.y + a0.y + a1.y + bv0.y;
    a.z = xv.z + a0.z + a1.z + bv0.z;
    a.w = xv.w + a0.w + a1.w + bv0.w;
    ((float4*)(aout + base))[tid] = a;
    float s  = a.x + a.y + a.z + a.w;
    float sq = a.x*a.x + a.y*a.y + a.z*a.z + a.w*a.w;
    #pragma unroll
    for (int off = 1; off < 64; off <<= 1) {
        s  += __shfl_xor(s, off);
        sq += __shfl_xor(sq, off);
    }
    __shared__ float ps[4], pq[4];
    int wave = tid >> 6;
    if ((tid & 63) == 0) { ps[wave] = s; pq[wave] = sq; }
    __syncthreads();
    s  = ps[0] + ps[1] + ps[2] + ps[3];
    sq = pq[0] + pq[1] + pq[2] + pq[3];
    float mean = s * (1.0f / Dm);
    float var  = sq * (1.0f / Dm) - mean * mean;
    float rstd = rsqrtf(var + 1e-5f);
    float4 gv = ((const float4*)g)[tid];
    float4 bbv = ((const float4*)b)[tid];
    float4 o;
    o.x = (a.x - mean) * rstd * gv.x + bbv.x;
    o.y = (a.y - mean) * rstd * gv.y + bbv.y;
    o.z = (a.z - mean) * rstd * gv.z + bbv.z;
    o.w = (a.w - mean) * rstd * gv.w + bbv.w;
    unsigned short t4[4] = { f2bf(o.x), f2bf(o.y), f2bf(o.z), f2bf(o.w) };
    *(uint2*)(h2b + base + tid * 4) = *(uint2*)t4;

    // ---- fused router ----
    float lg[8];
    #pragma unroll
    for (int e = 0; e < 8; e++) lg[e] = 0.0f;
    float oc[4] = { o.x, o.y, o.z, o.w };
    #pragma unroll
    for (int c = 0; c < 4; c++) {
        const float4* wr4 = (const float4*)(Wr + (size_t)(tid * 4 + c) * Ee);
        float4 wa = wr4[0], wb = wr4[1];
        lg[0] += oc[c]*wa.x; lg[1] += oc[c]*wa.y; lg[2] += oc[c]*wa.z; lg[3] += oc[c]*wa.w;
        lg[4] += oc[c]*wb.x; lg[5] += oc[c]*wb.y; lg[6] += oc[c]*wb.z; lg[7] += oc[c]*wb.w;
    }
    #pragma unroll
    for (int e = 0; e < 8; e++)
        #pragma unroll
        for (int off = 1; off < 64; off <<= 1) lg[e] += __shfl_xor(lg[e], off);
    __shared__ float wlg[4][8];
    if ((tid & 63) == 0) {
        #pragma unroll
        for (int e = 0; e < 8; e++) wlg[wave][e] = lg[e];
    }
    __syncthreads();
    if (tid == 0) {
        float l8[8];
        #pragma unroll
        for (int e = 0; e < 8; e++) l8[e] = wlg[0][e] + wlg[1][e] + wlg[2][e] + wlg[3][e] + br[e];
        float v1 = -INFINITY, v2 = -INFINITY;
        for (int e = 0; e < 8; e++) {
            float xv2 = l8[e];
            if (xv2 > v1) { v2 = v1; v1 = xv2; }
            else if (xv2 > v2) v2 = xv2;
        }
        float wv[8]; float denom = 0.0f;
        for (int e = 0; e < 8; e++) {
            if (l8[e] >= v2) { wv[e] = __expf(l8[e] - v1); denom += wv[e]; }
            else wv[e] = 0.0f;
        }
        float inv = 1.0f / denom;
        for (int e = 0; e < 8; e++) w_rt[row * Ee + e] = wv[e] * inv;
    }
}

// ---------------- Transpose+convert: src [Kk][Nn] fp32 -> dst [Nn][Kk] bf16 ----------------
__global__ __launch_bounds__(256) void tconv(const float* __restrict__ src,
                                             unsigned short* __restrict__ dst,
                                             int Kk, int Nn) {
    src += (size_t)blockIdx.z * Kk * Nn;
    dst += (size_t)blockIdx.z * Kk * Nn;
    int n0 = blockIdx.x * 64, k0 = blockIdx.y * 64;
    int tid = threadIdx.x;
    __shared__ float t[64][65];
    #pragma unroll
    for (int p = 0; p < 4; p++) {
        int kr = p * 16 + (tid >> 4);
        int nc = (tid & 15) * 4;
        float4 v = *(const float4*)(src + (size_t)(k0 + kr) * Nn + n0 + nc);
        t[kr][nc] = v.x; t[kr][nc+1] = v.y; t[kr][nc+2] = v.z; t[kr][nc+3] = v.w;
    }
    __syncthreads();
    int nr = tid >> 2;
    int kc = (tid & 3) * 16;
    unsigned short o[16];
    #pragma unroll
    for (int j = 0; j < 16; j++) o[j] = f2bf(t[kc + j][nr]);
    *(bf16x8*)(dst + (size_t)(n0 + nr) * Kk + k0 + kc)     = *(bf16x8*)&o[0];
    *(bf16x8*)(dst + (size_t)(n0 + nr) * Kk + k0 + kc + 8) = *(bf16x8*)&o[8];
}

// ---- Merged transpose for the four 1024x1024 attention weights (z picks src/dst) ----
__global__ __launch_bounds__(256) void tconv4(const float* __restrict__ s0,
                                              const float* __restrict__ s1,
                                              const float* __restrict__ s2,
                                              const float* __restrict__ s3,
                                              unsigned short* __restrict__ d0,
                                              unsigned short* __restrict__ d3) {
    int z = blockIdx.z;
    const float* src = (z == 0) ? s0 : (z == 1 ? s1 : (z == 2 ? s2 : s3));
    unsigned short* dst = (z < 3) ? d0 + (size_t)z * 1024 * 1024 : d3;
    int n0 = blockIdx.x * 64, k0 = blockIdx.y * 64;
    int tid = threadIdx.x;
    __shared__ float t[64][65];
    #pragma unroll
    for (int p = 0; p < 4; p++) {
        int kr = p * 16 + (tid >> 4);
        int nc = (tid & 15) * 4;
        float4 v = *(const float4*)(src + (size_t)(k0 + kr) * 1024 + n0 + nc);
        t[kr][nc] = v.x; t[kr][nc+1] = v.y; t[kr][nc+2] = v.z; t[kr][nc+3] = v.w;
    }
    __syncthreads();
    int nr = tid >> 2;
    int kc = (tid & 3) * 16;
    unsigned short o[16];
    #pragma unroll
    for (int j = 0; j < 16; j++) o[j] = f2bf(t[kc + j][nr]);
    *(bf16x8*)(dst + (size_t)(n0 + nr) * 1024 + k0 + kc)     = *(bf16x8*)&o[0];
    *(bf16x8*)(dst + (size_t)(n0 + nr) * 1024 + k0 + kc + 8) = *(bf16x8*)&o[8];
}

// -------- dbuf 128x128 GEMM (QKV / O-proj) --------
// MODE 0: QKV (bias by segment, out bf16 [S][3072])
// MODE 1: OProj (split-K2: z=kc, out fp32 partial [kc][S][Dm], no bias)
template<int MODE>
__global__ __launch_bounds__(256, 2) void gemm_db(const unsigned short* __restrict__ A,
                                                  const unsigned short* __restrict__ Wt,
                                                  const float* __restrict__ bias0,
                                                  const float* __restrict__ bias1,
                                                  const float* __restrict__ bias2,
                                                  void* __restrict__ Cout,
                                                  int M, int N, int K) {
    const int tid = threadIdx.x;
    const int lane = tid & 63;
    const int w = tid >> 6;
    const int lr = lane >> 4, lc = lane & 15;
    const int wr = w >> 1, wc = w & 1;

    int kc = (MODE == 1) ? blockIdx.z : 0;
    const int m0 = blockIdx.y * 128;
    const int n0 = blockIdx.x * 128;
    const int KL   = (MODE == 1) ? 512 : K;
    const int Koff = kc * KL;

    __shared__ __align__(16) unsigned short As[2][128 * 64];
    __shared__ __align__(16) unsigned short Bs[2][128 * 64];

    const int srow = lane >> 3;
    const int csw  = ((lane & 7) ^ srow) * 8;
    const unsigned short* asrc[4];
    const unsigned short* bsrc[4];
    #pragma unroll
    for (int i = 0; i < 4; i++) {
        int rl = w * 32 + i * 8 + srow;
        asrc[i] = A  + (size_t)(m0 + rl) * K + Koff + csw;
        bsrc[i] = Wt + (size_t)(n0 + rl) * K + Koff + csw;
    }

    f32x4 acc[4][4];
    #pragma unroll
    for (int a = 0; a < 4; a++)
        #pragma unroll
        for (int bb = 0; bb < 4; bb++) acc[a][bb] = (f32x4)0.0f;

    auto STAGE = [&](int buf, int kblk) {
        const size_t koff = (size_t)kblk * 64;
        #pragma unroll
        for (int i = 0; i < 4; i++) {
            gload16(asrc[i] + koff, &As[buf][(w * 32 + i * 8) * 64]);
            gload16(bsrc[i] + koff, &Bs[buf][(w * 32 + i * 8) * 64]);
        }
    };

    const int nt = KL / 64;
    STAGE(0, 0);
    for (int t = 0; t < nt; ++t) {
        const int cur = t & 1;
        if (t + 1 < nt) {
            STAGE(cur ^ 1, t + 1);
            asm volatile("s_waitcnt vmcnt(8)" ::: "memory");
        } else {
            asm volatile("s_waitcnt vmcnt(0)" ::: "memory");
        }
        __builtin_amdgcn_s_barrier();
        #pragma unroll
        for (int ks = 0; ks < 2; ks++) {
            const int ck = ((ks * 4 + lr) ^ (lc & 7)) * 8;
            bf16x8 af[4], bfv[4];
            #pragma unroll
            for (int fm = 0; fm < 4; fm++)
                af[fm] = *(const bf16x8*)&As[cur][(wr * 64 + fm * 16 + lc) * 64 + ck];
            #pragma unroll
            for (int fn = 0; fn < 4; fn++)
                bfv[fn] = *(const bf16x8*)&Bs[cur][(wc * 64 + fn * 16 + lc) * 64 + ck];
            #pragma unroll
            for (int fm = 0; fm < 4; fm++)
                #pragma unroll
                for (int fn = 0; fn < 4; fn++)
                    acc[fm][fn] = __builtin_amdgcn_mfma_f32_16x16x32_bf16(af[fm], bfv[fn], acc[fm][fn], 0, 0, 0);
        }
        asm volatile("" ::: "memory");
        __builtin_amdgcn_s_barrier();
    }

    #pragma unroll
    for (int fm = 0; fm < 4; fm++) {
        #pragma unroll
        for (int r = 0; r < 4; r++) {
            int m = m0 + wr * 64 + fm * 16 + lr * 4 + r;
            #pragma unroll
            for (int fn = 0; fn < 4; fn++) {
                int ncol = n0 + wc * 64 + fn * 16 + lc;
                float val = acc[fm][fn][r];
                if constexpr (MODE == 0) {
                    const float* bb = (ncol < 1024) ? bias0 : (ncol < 2048 ? bias1 : bias2);
                    val += bb[ncol & 1023];
                    ((unsigned short*)Cout)[(size_t)m * N + ncol] = f2bf(val);
                } else {
                    ((float*)Cout)[(size_t)kc * M * N + (size_t)m * N + ncol] = val;
                }
            }
        }
    }
}

// -------- MoE GEMM: m97 structure (128x128, BK=64, single-buf 32KB), 5 blocks/CU --------
// (R13's BK=32 + bounds-6 spilled accumulators: VGPR cap 85 < ~90 needed -> 1.4GB scratch
//  traffic. bounds-5 caps at 102 VGPR >= 64 used: no spill, LDS 5x32KB = 160KB exactly.)
// MODE 2: MoE up   (gather rows, GELU, out bf16 compact [slot][Ff])
// MODE 3: MoE down (A compact, split-K4 via blockIdx.z, out bf16 partial eo[kc][4096][Dm])
template<int MODE>
__global__ __launch_bounds__(256, 5) void gemm_moe(const unsigned short* __restrict__ A,
                                                   const unsigned short* __restrict__ Wt,
                                                   const float* __restrict__ bias,
                                                   void* __restrict__ Cout,
                                                   const int* __restrict__ rows,
                                                   const int* __restrict__ counts,
                                                   const int* __restrict__ offs,
                                                   const int* __restrict__ tilemap,
                                                   const int* __restrict__ ntiles,
                                                   int N, int K) {
    const int by = blockIdx.y;
    if (by >= *ntiles) return;
    const int tm = tilemap[by];
    const int e  = tm >> 8;
    const int m0 = (tm & 255) * 128;
    const int kc = (MODE == 3) ? blockIdx.z : 0;

    const int tid = threadIdx.x;
    const int lane = tid & 63;
    const int w = tid >> 6;
    const int lr = lane >> 4, lc = lane & 15;
    const int wr = w >> 1, wc = w & 1;

    const int Mcnt = counts[e];
    const int n0 = blockIdx.x * 128;
    const int KL = (MODE == 3) ? (K >> 2) : K;
    const int Koff = kc * KL;
    const unsigned short* Wz = Wt + (size_t)e * N * K;
    const float* biasz = bias + (size_t)e * N;
    const int zoff = offs[e];

    __shared__ __align__(16) unsigned short As[128 * 64];
    __shared__ __align__(16) unsigned short Bs[128 * 64];

    const int srow = lane >> 3;
    const int csw  = ((lane & 7) ^ srow) * 8;   // XOR-swizzled source chunk (involution)
    const unsigned short* asrc[4];
    const unsigned short* bsrc[4];
    #pragma unroll
    for (int i = 0; i < 4; i++) {
        int rl = w * 32 + i * 8 + srow;
        int ma = m0 + rl;
        int srcRow;
        if constexpr (MODE == 2) srcRow = rows[e * S + (ma < Mcnt ? ma : Mcnt - 1)];
        else                     srcRow = zoff + (ma < Mcnt ? ma : Mcnt - 1);
        asrc[i] = A  + (size_t)srcRow * K + Koff + csw;
        bsrc[i] = Wz + (size_t)(n0 + rl) * K + Koff + csw;
    }

    f32x4 acc[4][4];
    #pragma unroll
    for (int a = 0; a < 4; a++)
        #pragma unroll
        for (int bb = 0; bb < 4; bb++) acc[a][bb] = (f32x4)0.0f;

    for (int k0 = 0; k0 < KL; k0 += 64) {
        #pragma unroll
        for (int i = 0; i < 4; i++) {
            gload16(asrc[i] + k0, &As[(w * 32 + i * 8) * 64]);
            gload16(bsrc[i] + k0, &Bs[(w * 32 + i * 8) * 64]);
        }
        __syncthreads();
        #pragma unroll
        for (int ks = 0; ks < 2; ks++) {
            const int ck = ((ks * 4 + lr) ^ (lc & 7)) * 8;
            bf16x8 af[4], bfv[4];
            #pragma unroll
            for (int fm = 0; fm < 4; fm++)
                af[fm] = *(const bf16x8*)&As[(wr * 64 + fm * 16 + lc) * 64 + ck];
            #pragma unroll
            for (int fn = 0; fn < 4; fn++)
                bfv[fn] = *(const bf16x8*)&Bs[(wc * 64 + fn * 16 + lc) * 64 + ck];
            #pragma unroll
            for (int fm = 0; fm < 4; fm++)
                #pragma unroll
                for (int fn = 0; fn < 4; fn++)
                    acc[fm][fn] = __builtin_amdgcn_mfma_f32_16x16x32_bf16(af[fm], bfv[fn], acc[fm][fn], 0, 0, 0);
        }
        __syncthreads();
    }

    #pragma unroll
    for (int fm = 0; fm < 4; fm++) {
        #pragma unroll
        for (int r = 0; r < 4; r++) {
            int m = m0 + wr * 64 + fm * 16 + lr * 4 + r;
            if (m >= Mcnt) continue;
            #pragma unroll
            for (int fn = 0; fn < 4; fn++) {
                int ncol = n0 + wc * 64 + fn * 16 + lc;
                float val = acc[fm][fn][r];
                if constexpr (MODE == 2) {
                    val += biasz[ncol];
                    ((unsigned short*)Cout)[(size_t)(zoff + m) * N + ncol] = f2bf(gelu_f(val));
                } else {
                    if (kc == 0) val += biasz[ncol];
                    ((unsigned short*)Cout)[(size_t)kc * 4096 * N + (size_t)(zoff + m) * N + ncol] = f2bf(val);
                }
            }
        }
    }
}

// ---------------- MFMA flash attention: balanced pairing, 1 barrier/step, setprio ----------------
__global__ __launch_bounds__(256) void attn_mfma(const unsigned short* __restrict__ qkv,
                                                 unsigned short* __restrict__ ob) {
    int bid = blockIdx.x;
    int qt, h;
    if (bid < 256) { qt = 31 - (bid & 31); h = bid >> 5; }
    else           { qt = bid & 31;        h = 8 + ((bid - 256) >> 5); }
    int tid = threadIdx.x;
    int lane = tid & 63, w = tid >> 6;
    int lr = lane >> 4, lc = lane & 15;

    __shared__ __align__(16) unsigned short Kl[2][64 * 64];
    __shared__ __align__(16) unsigned short Vt[2][64 * 64];
    __shared__ __align__(16) unsigned short Pl[4][16 * 64];

    bf16x8 qf[2];
    int qg_base = qt * 64 + w * 16;
    {
        int qrow = qg_base + lc;
        #pragma unroll
        for (int ks = 0; ks < 2; ks++)
            qf[ks] = *(const bf16x8*)(qkv + (size_t)qrow * 3072 + h * 64 + ks * 32 + lr * 8);
    }

    const int srow = lane >> 3;
    const int scw  = ((lane & 7) ^ srow) * 8;
    const unsigned short* ksrc[2];
    #pragma unroll
    for (int i = 0; i < 2; i++)
        ksrc[i] = qkv + (size_t)(w * 16 + i * 8 + srow) * 3072 + h * 64 + 1024 + scw;
    int vrow[2], vcg[2];
    const unsigned short* vsrc[2];
    #pragma unroll
    for (int i = 0; i < 2; i++) {
        int u = tid + i * 256;
        vrow[i] = u >> 3; vcg[i] = (u & 7) * 8;
        vsrc[i] = qkv + (size_t)vrow[i] * 3072 + h * 64 + 2048 + vcg[i];
    }

    f32x4 oacc[4];
    #pragma unroll
    for (int fd = 0; fd < 4; fd++) oacc[fd] = (f32x4)0.0f;
    float mrun[4], lrun[4];
    #pragma unroll
    for (int r = 0; r < 4; r++) { mrun[r] = -INFINITY; lrun[r] = 0.0f; }

    bf16x8 vreg[2];
    vreg[0] = *(const bf16x8*)(vsrc[0]);
    vreg[1] = *(const bf16x8*)(vsrc[1]);
    gload16(ksrc[0], &Kl[0][(w * 16 + 0) * 64]);
    gload16(ksrc[1], &Kl[0][(w * 16 + 8) * 64]);
    #pragma unroll
    for (int i = 0; i < 2; i++)
        #pragma unroll
        for (int j = 0; j < 8; j++) {
            int d = vcg[i] + j;
            int ch = ((vrow[i] >> 3) ^ (d & 7) ^ (d >> 3)) & 7;
            Vt[0][d * 64 + ch * 8 + (vrow[i] & 7)] = (unsigned short)vreg[i][j];
        }
    __syncthreads();

    for (int kt = 0; kt <= qt; kt++) {
        const int cur = kt & 1;
        if (kt < qt) {
            size_t off = (size_t)(kt + 1) * 64 * 3072;
            vreg[0] = *(const bf16x8*)(vsrc[0] + off);
            vreg[1] = *(const bf16x8*)(vsrc[1] + off);
            gload16(ksrc[0] + off, &Kl[cur ^ 1][(w * 16 + 0) * 64]);
            gload16(ksrc[1] + off, &Kl[cur ^ 1][(w * 16 + 8) * 64]);
        }

        f32x4 sc[4];
        #pragma unroll
        for (int fn = 0; fn < 4; fn++) sc[fn] = (f32x4)0.0f;
        __builtin_amdgcn_s_setprio(1);
        #pragma unroll
        for (int fn = 0; fn < 4; fn++)
            #pragma unroll
            for (int ks = 0; ks < 2; ks++) {
                bf16x8 kf = *(const bf16x8*)&Kl[cur][(fn * 16 + lc) * 64 + ((ks * 4 + lr) ^ (lc & 7)) * 8];
                sc[fn] = __builtin_amdgcn_mfma_f32_16x16x32_bf16(qf[ks], kf, sc[fn], 0, 0, 0);
            }
        __builtin_amdgcn_s_setprio(0);

        float st[4][4];
        float mloc[4];
        #pragma unroll
        for (int r = 0; r < 4; r++) mloc[r] = -INFINITY;
        #pragma unroll
        for (int fn = 0; fn < 4; fn++)
            #pragma unroll
            for (int r = 0; r < 4; r++) {
                float sv = sc[fn][r] * 0.125f;
                if (kt == qt) {
                    int kvg = kt * 64 + fn * 16 + lc;
                    int qg  = qg_base + lr * 4 + r;
                    if (kvg > qg) sv = -INFINITY;
                }
                st[fn][r] = sv;
                mloc[r] = fmaxf(mloc[r], sv);
            }
        #pragma unroll
        for (int r = 0; r < 4; r++) {
            mloc[r] = fmaxf(mloc[r], __shfl_xor(mloc[r], 1));
            mloc[r] = fmaxf(mloc[r], __shfl_xor(mloc[r], 2));
            mloc[r] = fmaxf(mloc[r], __shfl_xor(mloc[r], 4));
            mloc[r] = fmaxf(mloc[r], __shfl_xor(mloc[r], 8));
        }
        float fsc[4], lpart[4];
        #pragma unroll
        for (int r = 0; r < 4; r++) {
            float mnew = fmaxf(mrun[r], mloc[r]);
            fsc[r] = __expf(mrun[r] - mnew);
            mrun[r] = mnew;
            lpart[r] = 0.0f;
        }
        float pv[4][4];
        #pragma unroll
        for (int fn = 0; fn < 4; fn++)
            #pragma unroll
            for (int r = 0; r < 4; r++) {
                pv[fn][r] = __expf(st[fn][r] - mrun[r]);
                lpart[r] += pv[fn][r];
            }
        #pragma unroll
        for (int r = 0; r < 4; r++) {
            lpart[r] += __shfl_xor(lpart[r], 1);
            lpart[r] += __shfl_xor(lpart[r], 2);
            lpart[r] += __shfl_xor(lpart[r], 4);
            lpart[r] += __shfl_xor(lpart[r], 8);
            lrun[r] = lrun[r] * fsc[r] + lpart[r];
        }
        #pragma unroll
        for (int fn = 0; fn < 4; fn++)
            #pragma unroll
            for (int r = 0; r < 4; r++) {
                int q = lr * 4 + r;
                int kvc = fn * 16 + lc;
                int ch = ((kvc >> 3) ^ (q & 7) ^ (q >> 3)) & 7;
                Pl[w][q * 64 + ch * 8 + (kvc & 7)] = f2bf(pv[fn][r]);
            }
        #pragma unroll
        for (int fd = 0; fd < 4; fd++)
            #pragma unroll
            for (int r = 0; r < 4; r++) oacc[fd][r] *= fsc[r];

        if (kt < qt) {
            #pragma unroll
            for (int i = 0; i < 2; i++)
                #pragma unroll
                for (int j = 0; j < 8; j++) {
                    int d = vcg[i] + j;
                    int ch = ((vrow[i] >> 3) ^ (d & 7) ^ (d >> 3)) & 7;
                    Vt[cur ^ 1][d * 64 + ch * 8 + (vrow[i] & 7)] = (unsigned short)vreg[i][j];
                }
        }

        __builtin_amdgcn_s_setprio(1);
        #pragma unroll
        for (int ks = 0; ks < 2; ks++) {
            int chp = ((ks * 4 + lr) ^ (lc & 7) ^ (lc >> 3)) & 7;
            bf16x8 pa = *(const bf16x8*)&Pl[w][lc * 64 + chp * 8];
            #pragma unroll
            for (int fd = 0; fd < 4; fd++) {
                int d = fd * 16 + lc;
                int chv = ((ks * 4 + lr) ^ (d & 7) ^ (d >> 3)) & 7;
                bf16x8 vb = *(const bf16x8*)&Vt[cur][d * 64 + chv * 8];
                oacc[fd] = __builtin_amdgcn_mfma_f32_16x16x32_bf16(pa, vb, oacc[fd], 0, 0, 0);
            }
        }
        __builtin_amdgcn_s_setprio(0);
        __syncthreads();
    }
    #pragma unroll
    for (int fd = 0; fd < 4; fd++)
        #pragma unroll
        for (int r = 0; r < 4; r++) {
            float val = oacc[fd][r] / lrun[r];
            ob[(size_t)(qg_base + lr * 4 + r) * 1024 + h * 64 + fd * 16 + lc] = f2bf(val);
        }
}

// ------- Token lists + offsets + token->slot map + compact tile map (single block) -------
__global__ __launch_bounds__(256) void listbuild_kernel(const float* __restrict__ w_rt,
                                                        int* __restrict__ rows,
                                                        int* __restrict__ counts,
                                                        int* __restrict__ offs,
                                                        int* __restrict__ tok2slot,
                                                        float* __restrict__ tokw,
                                                        int* __restrict__ tilemap,
                                                        int* __restrict__ ntiles) {
    int tid = threadIdx.x;
    __shared__ int sc[256];
    __shared__ int runoff_s;
    __shared__ int scounts[8];
    int ncnt[8];
    #pragma unroll
    for (int j = 0; j < 8; j++) ncnt[j] = 0;
    if (tid == 0) runoff_s = 0;
    __syncthreads();
    for (int e = 0; e < Ee; e++) {
        int t0 = tid * 8;
        int sel = 0, flags = 0;
        #pragma unroll
        for (int j = 0; j < 8; j++)
            if (w_rt[(size_t)(t0 + j) * Ee + e] > 0.0f) { flags |= 1 << j; sel++; }
        sc[tid] = sel;
        __syncthreads();
        for (int off = 1; off < 256; off <<= 1) {
            int add = (tid >= off) ? sc[tid - off] : 0;
            __syncthreads();
            sc[tid] += add;
            __syncthreads();
        }
        int base = runoff_s;
        int pos = sc[tid] - sel;
        #pragma unroll
        for (int j = 0; j < 8; j++) {
            if (flags & (1 << j)) {
                rows[e * S + pos] = t0 + j;
                int c = ncnt[j];
                if (c < 2) {
                    tok2slot[(t0 + j) * 2 + c] = base + pos;
                    tokw[(t0 + j) * 2 + c] = w_rt[(size_t)(t0 + j) * Ee + e];
                    ncnt[j] = c + 1;
                }
                pos++;
            }
        }
        __syncthreads();
        if (tid == 0) {
            offs[e] = base;
            counts[e] = sc[255];
            scounts[e] = sc[255];
            runoff_s = base + sc[255];
        }
        __syncthreads();
    }
    if (tid == 0) {
        int t = 0;
        for (int e = 0; e < Ee; e++) {
            int nmt = (scounts[e] + 127) >> 7;
            for (int mt = 0; mt < nmt; mt++) tilemap[t++] = (e << 8) | mt;
        }
        *ntiles = t;
        for (int j = t; j < 40; j++) tilemap[j] = 0;
    }
}

// -------- Combine: out[t] += w0*sum_p eo[p][s0] + w1*sum_p eo[p][s1]  (4 bf16 partials) --------
__global__ __launch_bounds__(256) void combine_kernel(float* __restrict__ out,
                                                      const unsigned short* __restrict__ eo,
                                                      const int* __restrict__ tok2slot,
                                                      const float* __restrict__ tokw) {
    int t = blockIdx.x, d = threadIdx.x;
    int s0 = tok2slot[t * 2], s1 = tok2slot[t * 2 + 1];
    float w0 = tokw[t * 2], w1 = tokw[t * 2 + 1];
    float4 o = ((const float4*)(out + (size_t)t * Dm))[d];
    float a[4] = {0,0,0,0}, b[4] = {0,0,0,0};
    #pragma unroll
    for (int p = 0; p < 4; p++) {
        const unsigned short* ep = eo + (size_t)p * 4096 * Dm;
        uint2 ra = *(const uint2*)(ep + (size_t)s0 * Dm + d * 4);
        uint2 rb = *(const uint2*)(ep + (size_t)s1 * Dm + d * 4);
        const unsigned short* pa16 = (const unsigned short*)&ra;
        const unsigned short* pb16 = (const unsigned short*)&rb;
        #pragma unroll
        for (int j = 0; j < 4; j++) { a[j] += bf2f(pa16[j]); b[j] += bf2f(pb16[j]); }
    }
    o.x += w0 * a[0] + w1 * b[0];
    o.y += w0 * a[1] + w1 * b[1];
    o.z += w0 * a[2] + w1 * b[2];
    o.w += w0 * a[3] + w1 * b[3];
    ((float4*)(out + (size_t)t * Dm))[d] = o;
}

extern "C" void kernel_launch(void* const* d_in, const int* in_sizes, int n_in,
                              void* d_out, int out_size, void* d_ws, size_t ws_size,
                              hipStream_t stream) {
    const float* x    = (const float*)d_in[0];
    const float* ln1g = (const float*)d_in[1];
    const float* ln1b = (const float*)d_in[2];
    const float* ln2g = (const float*)d_in[3];
    const float* ln2b = (const float*)d_in[4];
    const float* Wq   = (const float*)d_in[5];
    const float* bq   = (const float*)d_in[6];
    const float* Wk   = (const float*)d_in[7];
    const float* bk   = (const float*)d_in[8];
    const float* Wv   = (const float*)d_in[9];
    const float* bv   = (const float*)d_in[10];
    const float* Wo   = (const float*)d_in[11];
    const float* bo   = (const float*)d_in[12];
    const float* Wr   = (const float*)d_in[13];
    const float* br   = (const float*)d_in[14];
    const float* ew1  = (const float*)d_in[15];
    const float* eb1  = (const float*)d_in[16];
    const float* ew2  = (const float*)d_in[17];
    const float* eb2  = (const float*)d_in[18];
    float* out = (float*)d_out;

    char* wsb = (char*)d_ws;
    const size_t MB = 1 << 20;
    unsigned short* ew1T = (unsigned short*)(wsb);               //   0: 64 MB (dead after up)
    unsigned short* eo   = (unsigned short*)(wsb);               //   0: 32 MB = 4 bf16 partials (overlays ew1T)
    unsigned short* ew2T = (unsigned short*)(wsb + 64*MB);       //  64: 64 MB
    unsigned short* mid  = (unsigned short*)(wsb + 128*MB);      // 128: 32 MB [4096][Ff] bf16
    unsigned short* qkvT = (unsigned short*)(wsb + 160*MB);      // 160:  6 MB
    unsigned short* WoT  = (unsigned short*)(wsb + 166*MB);      // 166:  2 MB
    unsigned short* h_bf = (unsigned short*)(wsb + 168*MB);      // 168:  4 MB (dead after QKV)
    unsigned short* qkv  = (unsigned short*)(wsb + 172*MB);      // 172: 12 MB (dead after attn)
    float*          p01  = (float*)         (wsb + 168*MB);      // 168: 16 MB (overlays h_bf+qkv)
    unsigned short* ob   = (unsigned short*)(wsb + 184*MB);      // 184:  4 MB
    unsigned short* h2b  = (unsigned short*)(wsb + 196*MB);      // 196:  4 MB
    float*          w_rt = (float*)         (wsb + 200*MB);
    int*            rows = (int*)           (wsb + 200*MB + 65536);
    int*            counts   = rows + Ee * S;
    int*            offs     = counts + Ee;
    int*            tok2slot = offs + Ee;
    float*          tokw     = (float*)(tok2slot + 2 * S);
    int*            tilemap  = (int*)(tokw + 2 * S);
    int*            ntiles   = tilemap + 40;

    // ---- one-shot weight transpose+convert to bf16 [N][K] ----
    tconv4<<<dim3(16, 16, 4), 256, 0, stream>>>(Wq, Wk, Wv, Wo, qkvT, WoT);
    tconv<<<dim3(64, 16, 8), 256, 0, stream>>>(ew1, ew1T, Dm, Ff);
    tconv<<<dim3(16, 64, 8), 256, 0, stream>>>(ew2, ew2T, Ff, Dm);

    ln_kernel<<<S, 256, 0, stream>>>(x, ln1g, ln1b, h_bf);

    gemm_db<0><<<dim3(24, 16), 256, 0, stream>>>(h_bf, qkvT, bq, bk, bv,
        qkv, S, 3072, Dm);

    attn_mfma<<<dim3(512, 1), 256, 0, stream>>>(qkv, ob);

    gemm_db<1><<<dim3(8, 16, 2), 256, 0, stream>>>(ob, WoT, nullptr, nullptr, nullptr,
        p01, S, Dm, Dm);

    ln2_fused<<<S, 256, 0, stream>>>(x, p01, p01 + (size_t)S * Dm, bo, ln2g, ln2b,
                                     Wr, br, out, h2b, w_rt);
    listbuild_kernel<<<1, 256, 0, stream>>>(w_rt, rows, counts, offs, tok2slot, tokw,
                                            tilemap, ntiles);

    // MoE up: BK=64, 5 blocks/CU — grid 32n x 40mt
    gemm_moe<2><<<dim3(32, 40, 1), 256, 0, stream>>>(h2b, ew1T, eb1,
        mid, rows, counts, offs, tilemap, ntiles, Ff, Dm);

    // MoE down: split-K4, grid 8n x 40mt x 4kc
    gemm_moe<3><<<dim3(8, 40, 4), 256, 0, stream>>>(mid, ew2T, eb2,
        eo, rows, counts, offs, tilemap, ntiles, Dm, Ff);

    combine_kernel<<<S, 256, 0, stream>>>(out, eo, tok2slot, tokw);
}

// Round 15
// 367.379 us; speedup vs baseline: 2.2189x; 1.7986x over previous
//
#include <hip/hip_runtime.h>
#include <hip/hip_bf16.h>
#include <math.h>

#define S 2048
#define Dm 1024
#define Ee 8
#define Ff 4096

typedef __attribute__((ext_vector_type(8))) short bf16x8;
typedef __attribute__((ext_vector_type(4))) float f32x4;

__device__ __forceinline__ unsigned short f2bf(float f) {
    union { float f; unsigned int u; } c; c.f = f;
    unsigned int r = (c.u + 0x7fffu + ((c.u >> 16) & 1u)) >> 16;
    return (unsigned short)r;
}

__device__ __forceinline__ float bf2f(unsigned short u) {
    union { float f; unsigned int i; } c; c.i = ((unsigned int)u) << 16; return c.f;
}

__device__ __forceinline__ void gload16(const void* g, void* l) {
    __builtin_amdgcn_global_load_lds(
        (const __attribute__((address_space(1))) void*)g,
        (__attribute__((address_space(3))) void*)l, 16, 0, 0);
}

// gelu(x) = 0.5*x*(1+erf(x/sqrt2)); erf via A&S 7.1.26 poly at y=|x|/sqrt2.
__device__ __forceinline__ float gelu_f(float x) {
    float ax = fabsf(x) * 0.70710678118654752f;
    float t = 1.0f / (1.0f + 0.3275911f * ax);
    float p = t * (0.254829592f + t * (-0.284496736f + t * (1.421413741f +
              t * (-1.453152027f + t * 1.061405429f))));
    float er = 1.0f - p * __expf(-ax * ax);
    er = (x < 0.0f) ? -er : er;
    return 0.5f * x * (1.0f + er);
}

// ---------------- LayerNorm 1: writes bf16 ----------------
__global__ __launch_bounds__(256) void ln_kernel(const float* __restrict__ x,
                                                 const float* __restrict__ g,
                                                 const float* __restrict__ b,
                                                 unsigned short* __restrict__ obf) {
    int row = blockIdx.x;
    int tid = threadIdx.x;
    float4 v = ((const float4*)(x + (size_t)row * Dm))[tid];
    float s  = v.x + v.y + v.z + v.w;
    float sq = v.x*v.x + v.y*v.y + v.z*v.z + v.w*v.w;
    #pragma unroll
    for (int off = 1; off < 64; off <<= 1) {
        s  += __shfl_xor(s, off);
        sq += __shfl_xor(sq, off);
    }
    __shared__ float ps[4], pq[4];
    int wave = tid >> 6;
    if ((tid & 63) == 0) { ps[wave] = s; pq[wave] = sq; }
    __syncthreads();
    s  = ps[0] + ps[1] + ps[2] + ps[3];
    sq = pq[0] + pq[1] + pq[2] + pq[3];
    float mean = s * (1.0f / Dm);
    float var  = sq * (1.0f / Dm) - mean * mean;
    float rstd = rsqrtf(var + 1e-5f);
    float4 gv = ((const float4*)g)[tid];
    float4 bv = ((const float4*)b)[tid];
    float4 o;
    o.x = (v.x - mean) * rstd * gv.x + bv.x;
    o.y = (v.y - mean) * rstd * gv.y + bv.y;
    o.z = (v.z - mean) * rstd * gv.z + bv.z;
    o.w = (v.w - mean) * rstd * gv.w + bv.w;
    unsigned short t4[4] = { f2bf(o.x), f2bf(o.y), f2bf(o.z), f2bf(o.w) };
    *(uint2*)(obf + (size_t)row * Dm + tid * 4) = *(uint2*)t4;
}

// ---- Fused: a = x+p0+p1+bo ; out=a ; h2=LN2(a) -> bf16 ; router logits/top2 -> w_rt ----
__global__ __launch_bounds__(256) void ln2_fused(const float* __restrict__ x,
                                                 const float* __restrict__ p0,
                                                 const float* __restrict__ p1,
                                                 const float* __restrict__ bo,
                                                 const float* __restrict__ g,
                                                 const float* __restrict__ b,
                                                 const float* __restrict__ Wr,
                                                 const float* __restrict__ br,
                                                 float* __restrict__ aout,
                                                 unsigned short* __restrict__ h2b,
                                                 float* __restrict__ w_rt) {
    int row = blockIdx.x;
    int tid = threadIdx.x;
    size_t base = (size_t)row * Dm;
    float4 xv = ((const float4*)(x + base))[tid];
    float4 a0 = ((const float4*)(p0 + base))[tid];
    float4 a1 = ((const float4*)(p1 + base))[tid];
    float4 bv0 = ((const float4*)bo)[tid];
    float4 a;
    a.x = xv.x + a0.x + a1.x + bv0.x;
    a.y = xv.y + a0.y + a1.y + bv0.y;
    a.z = xv.z + a0.z + a1.z + bv0.z;
    a.w = xv.w + a0.w + a1.w + bv0.w;
    ((float4*)(aout + base))[tid] = a;
    float s  = a.x + a.y + a.z + a.w;
    float sq = a.x*a.x + a.y*a.y + a.z*a.z + a.w*a.w;
    #pragma unroll
    for (int off = 1; off < 64; off <<= 1) {
        s  += __shfl_xor(s, off);
        sq += __shfl_xor(sq, off);
    }
    __shared__ float ps[4], pq[4];
    int wave = tid >> 6;
    if ((tid & 63) == 0) { ps[wave] = s; pq[wave] = sq; }
    __syncthreads();
    s  = ps[0] + ps[1] + ps[2] + ps[3];
    sq = pq[0] + pq[1] + pq[2] + pq[3];
    float mean = s * (1.0f / Dm);
    float var  = sq * (1.0f / Dm) - mean * mean;
    float rstd = rsqrtf(var + 1e-5f);
    float4 gv = ((const float4*)g)[tid];
    float4 bbv = ((const float4*)b)[tid];
    float4 o;
    o.x = (a.x - mean) * rstd * gv.x + bbv.x;
    o.y = (a.y - mean) * rstd * gv.y + bbv.y;
    o.z = (a.z - mean) * rstd * gv.z + bbv.z;
    o.w = (a.w - mean) * rstd * gv.w + bbv.w;
    unsigned short t4[4] = { f2bf(o.x), f2bf(o.y), f2bf(o.z), f2bf(o.w) };
    *(uint2*)(h2b + base + tid * 4) = *(uint2*)t4;

    // ---- fused router ----
    float lg[8];
    #pragma unroll
    for (int e = 0; e < 8; e++) lg[e] = 0.0f;
    float oc[4] = { o.x, o.y, o.z, o.w };
    #pragma unroll
    for (int c = 0; c < 4; c++) {
        const float4* wr4 = (const float4*)(Wr + (size_t)(tid * 4 + c) * Ee);
        float4 wa = wr4[0], wb = wr4[1];
        lg[0] += oc[c]*wa.x; lg[1] += oc[c]*wa.y; lg[2] += oc[c]*wa.z; lg[3] += oc[c]*wa.w;
        lg[4] += oc[c]*wb.x; lg[5] += oc[c]*wb.y; lg[6] += oc[c]*wb.z; lg[7] += oc[c]*wb.w;
    }
    #pragma unroll
    for (int e = 0; e < 8; e++)
        #pragma unroll
        for (int off = 1; off < 64; off <<= 1) lg[e] += __shfl_xor(lg[e], off);
    __shared__ float wlg[4][8];
    if ((tid & 63) == 0) {
        #pragma unroll
        for (int e = 0; e < 8; e++) wlg[wave][e] = lg[e];
    }
    __syncthreads();
    if (tid == 0) {
        float l8[8];
        #pragma unroll
        for (int e = 0; e < 8; e++) l8[e] = wlg[0][e] + wlg[1][e] + wlg[2][e] + wlg[3][e] + br[e];
        float v1 = -INFINITY, v2 = -INFINITY;
        for (int e = 0; e < 8; e++) {
            float xv2 = l8[e];
            if (xv2 > v1) { v2 = v1; v1 = xv2; }
            else if (xv2 > v2) v2 = xv2;
        }
        float wv[8]; float denom = 0.0f;
        for (int e = 0; e < 8; e++) {
            if (l8[e] >= v2) { wv[e] = __expf(l8[e] - v1); denom += wv[e]; }
            else wv[e] = 0.0f;
        }
        float inv = 1.0f / denom;
        for (int e = 0; e < 8; e++) w_rt[row * Ee + e] = wv[e] * inv;
    }
}

// ---------------- Transpose+convert: src [Kk][Nn] fp32 -> dst [Nn][Kk] bf16 ----------------
__global__ __launch_bounds__(256) void tconv(const float* __restrict__ src,
                                             unsigned short* __restrict__ dst,
                                             int Kk, int Nn) {
    src += (size_t)blockIdx.z * Kk * Nn;
    dst += (size_t)blockIdx.z * Kk * Nn;
    int n0 = blockIdx.x * 64, k0 = blockIdx.y * 64;
    int tid = threadIdx.x;
    __shared__ float t[64][65];
    #pragma unroll
    for (int p = 0; p < 4; p++) {
        int kr = p * 16 + (tid >> 4);
        int nc = (tid & 15) * 4;
        float4 v = *(const float4*)(src + (size_t)(k0 + kr) * Nn + n0 + nc);
        t[kr][nc] = v.x; t[kr][nc+1] = v.y; t[kr][nc+2] = v.z; t[kr][nc+3] = v.w;
    }
    __syncthreads();
    int nr = tid >> 2;
    int kc = (tid & 3) * 16;
    unsigned short o[16];
    #pragma unroll
    for (int j = 0; j < 16; j++) o[j] = f2bf(t[kc + j][nr]);
    *(bf16x8*)(dst + (size_t)(n0 + nr) * Kk + k0 + kc)     = *(bf16x8*)&o[0];
    *(bf16x8*)(dst + (size_t)(n0 + nr) * Kk + k0 + kc + 8) = *(bf16x8*)&o[8];
}

// ---- Merged transpose for the four 1024x1024 attention weights (z picks src/dst) ----
__global__ __launch_bounds__(256) void tconv4(const float* __restrict__ s0,
                                              const float* __restrict__ s1,
                                              const float* __restrict__ s2,
                                              const float* __restrict__ s3,
                                              unsigned short* __restrict__ d0,
                                              unsigned short* __restrict__ d3) {
    int z = blockIdx.z;
    const float* src = (z == 0) ? s0 : (z == 1 ? s1 : (z == 2 ? s2 : s3));
    unsigned short* dst = (z < 3) ? d0 + (size_t)z * 1024 * 1024 : d3;
    int n0 = blockIdx.x * 64, k0 = blockIdx.y * 64;
    int tid = threadIdx.x;
    __shared__ float t[64][65];
    #pragma unroll
    for (int p = 0; p < 4; p++) {
        int kr = p * 16 + (tid >> 4);
        int nc = (tid & 15) * 4;
        float4 v = *(const float4*)(src + (size_t)(k0 + kr) * 1024 + n0 + nc);
        t[kr][nc] = v.x; t[kr][nc+1] = v.y; t[kr][nc+2] = v.z; t[kr][nc+3] = v.w;
    }
    __syncthreads();
    int nr = tid >> 2;
    int kc = (tid & 3) * 16;
    unsigned short o[16];
    #pragma unroll
    for (int j = 0; j < 16; j++) o[j] = f2bf(t[kc + j][nr]);
    *(bf16x8*)(dst + (size_t)(n0 + nr) * 1024 + k0 + kc)     = *(bf16x8*)&o[0];
    *(bf16x8*)(dst + (size_t)(n0 + nr) * 1024 + k0 + kc + 8) = *(bf16x8*)&o[8];
}

// -------- dbuf 128x128 GEMM (QKV / O-proj) --------
// MODE 0: QKV (bias by segment, out bf16 [S][3072])
// MODE 1: OProj (split-K2: z=kc, out fp32 partial [kc][S][Dm], no bias)
template<int MODE>
__global__ __launch_bounds__(256, 2) void gemm_db(const unsigned short* __restrict__ A,
                                                  const unsigned short* __restrict__ Wt,
                                                  const float* __restrict__ bias0,
                                                  const float* __restrict__ bias1,
                                                  const float* __restrict__ bias2,
                                                  void* __restrict__ Cout,
                                                  int M, int N, int K) {
    const int tid = threadIdx.x;
    const int lane = tid & 63;
    const int w = tid >> 6;
    const int lr = lane >> 4, lc = lane & 15;
    const int wr = w >> 1, wc = w & 1;

    int kc = (MODE == 1) ? blockIdx.z : 0;
    const int m0 = blockIdx.y * 128;
    const int n0 = blockIdx.x * 128;
    const int KL   = (MODE == 1) ? 512 : K;
    const int Koff = kc * KL;

    __shared__ __align__(16) unsigned short As[2][128 * 64];
    __shared__ __align__(16) unsigned short Bs[2][128 * 64];

    const int srow = lane >> 3;
    const int csw  = ((lane & 7) ^ srow) * 8;
    const unsigned short* asrc[4];
    const unsigned short* bsrc[4];
    #pragma unroll
    for (int i = 0; i < 4; i++) {
        int rl = w * 32 + i * 8 + srow;
        asrc[i] = A  + (size_t)(m0 + rl) * K + Koff + csw;
        bsrc[i] = Wt + (size_t)(n0 + rl) * K + Koff + csw;
    }

    f32x4 acc[4][4];
    #pragma unroll
    for (int a = 0; a < 4; a++)
        #pragma unroll
        for (int bb = 0; bb < 4; bb++) acc[a][bb] = (f32x4)0.0f;

    auto STAGE = [&](int buf, int kblk) {
        const size_t koff = (size_t)kblk * 64;
        #pragma unroll
        for (int i = 0; i < 4; i++) {
            gload16(asrc[i] + koff, &As[buf][(w * 32 + i * 8) * 64]);
            gload16(bsrc[i] + koff, &Bs[buf][(w * 32 + i * 8) * 64]);
        }
    };

    const int nt = KL / 64;
    STAGE(0, 0);
    for (int t = 0; t < nt; ++t) {
        const int cur = t & 1;
        if (t + 1 < nt) {
            STAGE(cur ^ 1, t + 1);
            asm volatile("s_waitcnt vmcnt(8)" ::: "memory");
        } else {
            asm volatile("s_waitcnt vmcnt(0)" ::: "memory");
        }
        __builtin_amdgcn_s_barrier();
        #pragma unroll
        for (int ks = 0; ks < 2; ks++) {
            const int ck = ((ks * 4 + lr) ^ (lc & 7)) * 8;
            bf16x8 af[4], bfv[4];
            #pragma unroll
            for (int fm = 0; fm < 4; fm++)
                af[fm] = *(const bf16x8*)&As[cur][(wr * 64 + fm * 16 + lc) * 64 + ck];
            #pragma unroll
            for (int fn = 0; fn < 4; fn++)
                bfv[fn] = *(const bf16x8*)&Bs[cur][(wc * 64 + fn * 16 + lc) * 64 + ck];
            #pragma unroll
            for (int fm = 0; fm < 4; fm++)
                #pragma unroll
                for (int fn = 0; fn < 4; fn++)
                    acc[fm][fn] = __builtin_amdgcn_mfma_f32_16x16x32_bf16(af[fm], bfv[fn], acc[fm][fn], 0, 0, 0);
        }
        asm volatile("" ::: "memory");
        __builtin_amdgcn_s_barrier();
    }

    #pragma unroll
    for (int fm = 0; fm < 4; fm++) {
        #pragma unroll
        for (int r = 0; r < 4; r++) {
            int m = m0 + wr * 64 + fm * 16 + lr * 4 + r;
            #pragma unroll
            for (int fn = 0; fn < 4; fn++) {
                int ncol = n0 + wc * 64 + fn * 16 + lc;
                float val = acc[fm][fn][r];
                if constexpr (MODE == 0) {
                    const float* bb = (ncol < 1024) ? bias0 : (ncol < 2048 ? bias1 : bias2);
                    val += bb[ncol & 1023];
                    ((unsigned short*)Cout)[(size_t)m * N + ncol] = f2bf(val);
                } else {
                    ((float*)Cout)[(size_t)kc * M * N + (size_t)m * N + ncol] = val;
                }
            }
        }
    }
}

// -------- MoE GEMM: m97 structure (128x128, BK=64, single-buf 32KB), 4 blocks/CU --------
// NOTE: bounds (256,5) and (256,6) both SPILL (occupancy quantization forces VGPR<=64
// while kernel needs ~90): R13 1.4GB / R14 0.37GB scratch traffic. (256,4) is the max
// non-spilling occupancy — measured clean in R11/R12 (VGPR 64, WRITE 33MB, 76us).
// MODE 2: MoE up   (gather rows, GELU, out bf16 compact [slot][Ff])
// MODE 3: MoE down (A compact, split-K4 via blockIdx.z, out bf16 partial eo[kc][4096][Dm])
template<int MODE>
__global__ __launch_bounds__(256, 4) void gemm_moe(const unsigned short* __restrict__ A,
                                                   const unsigned short* __restrict__ Wt,
                                                   const float* __restrict__ bias,
                                                   void* __restrict__ Cout,
                                                   const int* __restrict__ rows,
                                                   const int* __restrict__ counts,
                                                   const int* __restrict__ offs,
                                                   const int* __restrict__ tilemap,
                                                   const int* __restrict__ ntiles,
                                                   int N, int K) {
    const int by = blockIdx.y;
    if (by >= *ntiles) return;
    const int tm = tilemap[by];
    const int e  = tm >> 8;
    const int m0 = (tm & 255) * 128;
    const int kc = (MODE == 3) ? blockIdx.z : 0;

    const int tid = threadIdx.x;
    const int lane = tid & 63;
    const int w = tid >> 6;
    const int lr = lane >> 4, lc = lane & 15;
    const int wr = w >> 1, wc = w & 1;

    const int Mcnt = counts[e];
    const int n0 = blockIdx.x * 128;
    const int KL = (MODE == 3) ? (K >> 2) : K;
    const int Koff = kc * KL;
    const unsigned short* Wz = Wt + (size_t)e * N * K;
    const float* biasz = bias + (size_t)e * N;
    const int zoff = offs[e];

    __shared__ __align__(16) unsigned short As[128 * 64];
    __shared__ __align__(16) unsigned short Bs[128 * 64];

    const int srow = lane >> 3;
    const int csw  = ((lane & 7) ^ srow) * 8;   // XOR-swizzled source chunk (involution)
    const unsigned short* asrc[4];
    const unsigned short* bsrc[4];
    #pragma unroll
    for (int i = 0; i < 4; i++) {
        int rl = w * 32 + i * 8 + srow;
        int ma = m0 + rl;
        int srcRow;
        if constexpr (MODE == 2) srcRow = rows[e * S + (ma < Mcnt ? ma : Mcnt - 1)];
        else                     srcRow = zoff + (ma < Mcnt ? ma : Mcnt - 1);
        asrc[i] = A  + (size_t)srcRow * K + Koff + csw;
        bsrc[i] = Wz + (size_t)(n0 + rl) * K + Koff + csw;
    }

    f32x4 acc[4][4];
    #pragma unroll
    for (int a = 0; a < 4; a++)
        #pragma unroll
        for (int bb = 0; bb < 4; bb++) acc[a][bb] = (f32x4)0.0f;

    for (int k0 = 0; k0 < KL; k0 += 64) {
        #pragma unroll
        for (int i = 0; i < 4; i++) {
            gload16(asrc[i] + k0, &As[(w * 32 + i * 8) * 64]);
            gload16(bsrc[i] + k0, &Bs[(w * 32 + i * 8) * 64]);
        }
        __syncthreads();
        #pragma unroll
        for (int ks = 0; ks < 2; ks++) {
            const int ck = ((ks * 4 + lr) ^ (lc & 7)) * 8;
            bf16x8 af[4], bfv[4];
            #pragma unroll
            for (int fm = 0; fm < 4; fm++)
                af[fm] = *(const bf16x8*)&As[(wr * 64 + fm * 16 + lc) * 64 + ck];
            #pragma unroll
            for (int fn = 0; fn < 4; fn++)
                bfv[fn] = *(const bf16x8*)&Bs[(wc * 64 + fn * 16 + lc) * 64 + ck];
            #pragma unroll
            for (int fm = 0; fm < 4; fm++)
                #pragma unroll
                for (int fn = 0; fn < 4; fn++)
                    acc[fm][fn] = __builtin_amdgcn_mfma_f32_16x16x32_bf16(af[fm], bfv[fn], acc[fm][fn], 0, 0, 0);
        }
        __syncthreads();
    }

    #pragma unroll
    for (int fm = 0; fm < 4; fm++) {
        #pragma unroll
        for (int r = 0; r < 4; r++) {
            int m = m0 + wr * 64 + fm * 16 + lr * 4 + r;
            if (m >= Mcnt) continue;
            #pragma unroll
            for (int fn = 0; fn < 4; fn++) {
                int ncol = n0 + wc * 64 + fn * 16 + lc;
                float val = acc[fm][fn][r];
                if constexpr (MODE == 2) {
                    val += biasz[ncol];
                    ((unsigned short*)Cout)[(size_t)(zoff + m) * N + ncol] = f2bf(gelu_f(val));
                } else {
                    if (kc == 0) val += biasz[ncol];
                    ((unsigned short*)Cout)[(size_t)kc * 4096 * N + (size_t)(zoff + m) * N + ncol] = f2bf(val);
                }
            }
        }
    }
}

// ---------------- MFMA flash attention: balanced pairing, 1 barrier/step, setprio ----------------
__global__ __launch_bounds__(256) void attn_mfma(const unsigned short* __restrict__ qkv,
                                                 unsigned short* __restrict__ ob) {
    int bid = blockIdx.x;
    int qt, h;
    if (bid < 256) { qt = 31 - (bid & 31); h = bid >> 5; }
    else           { qt = bid & 31;        h = 8 + ((bid - 256) >> 5); }
    int tid = threadIdx.x;
    int lane = tid & 63, w = tid >> 6;
    int lr = lane >> 4, lc = lane & 15;

    __shared__ __align__(16) unsigned short Kl[2][64 * 64];
    __shared__ __align__(16) unsigned short Vt[2][64 * 64];
    __shared__ __align__(16) unsigned short Pl[4][16 * 64];

    bf16x8 qf[2];
    int qg_base = qt * 64 + w * 16;
    {
        int qrow = qg_base + lc;
        #pragma unroll
        for (int ks = 0; ks < 2; ks++)
            qf[ks] = *(const bf16x8*)(qkv + (size_t)qrow * 3072 + h * 64 + ks * 32 + lr * 8);
    }

    const int srow = lane >> 3;
    const int scw  = ((lane & 7) ^ srow) * 8;
    const unsigned short* ksrc[2];
    #pragma unroll
    for (int i = 0; i < 2; i++)
        ksrc[i] = qkv + (size_t)(w * 16 + i * 8 + srow) * 3072 + h * 64 + 1024 + scw;
    int vrow[2], vcg[2];
    const unsigned short* vsrc[2];
    #pragma unroll
    for (int i = 0; i < 2; i++) {
        int u = tid + i * 256;
        vrow[i] = u >> 3; vcg[i] = (u & 7) * 8;
        vsrc[i] = qkv + (size_t)vrow[i] * 3072 + h * 64 + 2048 + vcg[i];
    }

    f32x4 oacc[4];
    #pragma unroll
    for (int fd = 0; fd < 4; fd++) oacc[fd] = (f32x4)0.0f;
    float mrun[4], lrun[4];
    #pragma unroll
    for (int r = 0; r < 4; r++) { mrun[r] = -INFINITY; lrun[r] = 0.0f; }

    bf16x8 vreg[2];
    vreg[0] = *(const bf16x8*)(vsrc[0]);
    vreg[1] = *(const bf16x8*)(vsrc[1]);
    gload16(ksrc[0], &Kl[0][(w * 16 + 0) * 64]);
    gload16(ksrc[1], &Kl[0][(w * 16 + 8) * 64]);
    #pragma unroll
    for (int i = 0; i < 2; i++)
        #pragma unroll
        for (int j = 0; j < 8; j++) {
            int d = vcg[i] + j;
            int ch = ((vrow[i] >> 3) ^ (d & 7) ^ (d >> 3)) & 7;
            Vt[0][d * 64 + ch * 8 + (vrow[i] & 7)] = (unsigned short)vreg[i][j];
        }
    __syncthreads();

    for (int kt = 0; kt <= qt; kt++) {
        const int cur = kt & 1;
        if (kt < qt) {
            size_t off = (size_t)(kt + 1) * 64 * 3072;
            vreg[0] = *(const bf16x8*)(vsrc[0] + off);
            vreg[1] = *(const bf16x8*)(vsrc[1] + off);
            gload16(ksrc[0] + off, &Kl[cur ^ 1][(w * 16 + 0) * 64]);
            gload16(ksrc[1] + off, &Kl[cur ^ 1][(w * 16 + 8) * 64]);
        }

        f32x4 sc[4];
        #pragma unroll
        for (int fn = 0; fn < 4; fn++) sc[fn] = (f32x4)0.0f;
        __builtin_amdgcn_s_setprio(1);
        #pragma unroll
        for (int fn = 0; fn < 4; fn++)
            #pragma unroll
            for (int ks = 0; ks < 2; ks++) {
                bf16x8 kf = *(const bf16x8*)&Kl[cur][(fn * 16 + lc) * 64 + ((ks * 4 + lr) ^ (lc & 7)) * 8];
                sc[fn] = __builtin_amdgcn_mfma_f32_16x16x32_bf16(qf[ks], kf, sc[fn], 0, 0, 0);
            }
        __builtin_amdgcn_s_setprio(0);

        float st[4][4];
        float mloc[4];
        #pragma unroll
        for (int r = 0; r < 4; r++) mloc[r] = -INFINITY;
        #pragma unroll
        for (int fn = 0; fn < 4; fn++)
            #pragma unroll
            for (int r = 0; r < 4; r++) {
                float sv = sc[fn][r] * 0.125f;
                if (kt == qt) {
                    int kvg = kt * 64 + fn * 16 + lc;
                    int qg  = qg_base + lr * 4 + r;
                    if (kvg > qg) sv = -INFINITY;
                }
                st[fn][r] = sv;
                mloc[r] = fmaxf(mloc[r], sv);
            }
        #pragma unroll
        for (int r = 0; r < 4; r++) {
            mloc[r] = fmaxf(mloc[r], __shfl_xor(mloc[r], 1));
            mloc[r] = fmaxf(mloc[r], __shfl_xor(mloc[r], 2));
            mloc[r] = fmaxf(mloc[r], __shfl_xor(mloc[r], 4));
            mloc[r] = fmaxf(mloc[r], __shfl_xor(mloc[r], 8));
        }
        float fsc[4], lpart[4];
        #pragma unroll
        for (int r = 0; r < 4; r++) {
            float mnew = fmaxf(mrun[r], mloc[r]);
            fsc[r] = __expf(mrun[r] - mnew);
            mrun[r] = mnew;
            lpart[r] = 0.0f;
        }
        float pv[4][4];
        #pragma unroll
        for (int fn = 0; fn < 4; fn++)
            #pragma unroll
            for (int r = 0; r < 4; r++) {
                pv[fn][r] = __expf(st[fn][r] - mrun[r]);
                lpart[r] += pv[fn][r];
            }
        #pragma unroll
        for (int r = 0; r < 4; r++) {
            lpart[r] += __shfl_xor(lpart[r], 1);
            lpart[r] += __shfl_xor(lpart[r], 2);
            lpart[r] += __shfl_xor(lpart[r], 4);
            lpart[r] += __shfl_xor(lpart[r], 8);
            lrun[r] = lrun[r] * fsc[r] + lpart[r];
        }
        #pragma unroll
        for (int fn = 0; fn < 4; fn++)
            #pragma unroll
            for (int r = 0; r < 4; r++) {
                int q = lr * 4 + r;
                int kvc = fn * 16 + lc;
                int ch = ((kvc >> 3) ^ (q & 7) ^ (q >> 3)) & 7;
                Pl[w][q * 64 + ch * 8 + (kvc & 7)] = f2bf(pv[fn][r]);
            }
        #pragma unroll
        for (int fd = 0; fd < 4; fd++)
            #pragma unroll
            for (int r = 0; r < 4; r++) oacc[fd][r] *= fsc[r];

        if (kt < qt) {
            #pragma unroll
            for (int i = 0; i < 2; i++)
                #pragma unroll
                for (int j = 0; j < 8; j++) {
                    int d = vcg[i] + j;
                    int ch = ((vrow[i] >> 3) ^ (d & 7) ^ (d >> 3)) & 7;
                    Vt[cur ^ 1][d * 64 + ch * 8 + (vrow[i] & 7)] = (unsigned short)vreg[i][j];
                }
        }

        __builtin_amdgcn_s_setprio(1);
        #pragma unroll
        for (int ks = 0; ks < 2; ks++) {
            int chp = ((ks * 4 + lr) ^ (lc & 7) ^ (lc >> 3)) & 7;
            bf16x8 pa = *(const bf16x8*)&Pl[w][lc * 64 + chp * 8];
            #pragma unroll
            for (int fd = 0; fd < 4; fd++) {
                int d = fd * 16 + lc;
                int chv = ((ks * 4 + lr) ^ (d & 7) ^ (d >> 3)) & 7;
                bf16x8 vb = *(const bf16x8*)&Vt[cur][d * 64 + chv * 8];
                oacc[fd] = __builtin_amdgcn_mfma_f32_16x16x32_bf16(pa, vb, oacc[fd], 0, 0, 0);
            }
        }
        __builtin_amdgcn_s_setprio(0);
        __syncthreads();
    }
    #pragma unroll
    for (int fd = 0; fd < 4; fd++)
        #pragma unroll
        for (int r = 0; r < 4; r++) {
            float val = oacc[fd][r] / lrun[r];
            ob[(size_t)(qg_base + lr * 4 + r) * 1024 + h * 64 + fd * 16 + lc] = f2bf(val);
        }
}

// ------- Token lists + offsets + token->slot map + compact tile map (single block) -------
__global__ __launch_bounds__(256) void listbuild_kernel(const float* __restrict__ w_rt,
                                                        int* __restrict__ rows,
                                                        int* __restrict__ counts,
                                                        int* __restrict__ offs,
                                                        int* __restrict__ tok2slot,
                                                        float* __restrict__ tokw,
                                                        int* __restrict__ tilemap,
                                                        int* __restrict__ ntiles) {
    int tid = threadIdx.x;
    __shared__ int sc[256];
    __shared__ int runoff_s;
    __shared__ int scounts[8];
    int ncnt[8];
    #pragma unroll
    for (int j = 0; j < 8; j++) ncnt[j] = 0;
    if (tid == 0) runoff_s = 0;
    __syncthreads();
    for (int e = 0; e < Ee; e++) {
        int t0 = tid * 8;
        int sel = 0, flags = 0;
        #pragma unroll
        for (int j = 0; j < 8; j++)
            if (w_rt[(size_t)(t0 + j) * Ee + e] > 0.0f) { flags |= 1 << j; sel++; }
        sc[tid] = sel;
        __syncthreads();
        for (int off = 1; off < 256; off <<= 1) {
            int add = (tid >= off) ? sc[tid - off] : 0;
            __syncthreads();
            sc[tid] += add;
            __syncthreads();
        }
        int base = runoff_s;
        int pos = sc[tid] - sel;
        #pragma unroll
        for (int j = 0; j < 8; j++) {
            if (flags & (1 << j)) {
                rows[e * S + pos] = t0 + j;
                int c = ncnt[j];
                if (c < 2) {
                    tok2slot[(t0 + j) * 2 + c] = base + pos;
                    tokw[(t0 + j) * 2 + c] = w_rt[(size_t)(t0 + j) * Ee + e];
                    ncnt[j] = c + 1;
                }
                pos++;
            }
        }
        __syncthreads();
        if (tid == 0) {
            offs[e] = base;
            counts[e] = sc[255];
            scounts[e] = sc[255];
            runoff_s = base + sc[255];
        }
        __syncthreads();
    }
    if (tid == 0) {
        int t = 0;
        for (int e = 0; e < Ee; e++) {
            int nmt = (scounts[e] + 127) >> 7;
            for (int mt = 0; mt < nmt; mt++) tilemap[t++] = (e << 8) | mt;
        }
        *ntiles = t;
        for (int j = t; j < 40; j++) tilemap[j] = 0;
    }
}

// -------- Combine: out[t] += w0*sum_p eo[p][s0] + w1*sum_p eo[p][s1]  (4 bf16 partials) --------
__global__ __launch_bounds__(256) void combine_kernel(float* __restrict__ out,
                                                      const unsigned short* __restrict__ eo,
                                                      const int* __restrict__ tok2slot,
                                                      const float* __restrict__ tokw) {
    int t = blockIdx.x, d = threadIdx.x;
    int s0 = tok2slot[t * 2], s1 = tok2slot[t * 2 + 1];
    float w0 = tokw[t * 2], w1 = tokw[t * 2 + 1];
    float4 o = ((const float4*)(out + (size_t)t * Dm))[d];
    float a[4] = {0,0,0,0}, b[4] = {0,0,0,0};
    #pragma unroll
    for (int p = 0; p < 4; p++) {
        const unsigned short* ep = eo + (size_t)p * 4096 * Dm;
        uint2 ra = *(const uint2*)(ep + (size_t)s0 * Dm + d * 4);
        uint2 rb = *(const uint2*)(ep + (size_t)s1 * Dm + d * 4);
        const unsigned short* pa16 = (const unsigned short*)&ra;
        const unsigned short* pb16 = (const unsigned short*)&rb;
        #pragma unroll
        for (int j = 0; j < 4; j++) { a[j] += bf2f(pa16[j]); b[j] += bf2f(pb16[j]); }
    }
    o.x += w0 * a[0] + w1 * b[0];
    o.y += w0 * a[1] + w1 * b[1];
    o.z += w0 * a[2] + w1 * b[2];
    o.w += w0 * a[3] + w1 * b[3];
    ((float4*)(out + (size_t)t * Dm))[d] = o;
}

extern "C" void kernel_launch(void* const* d_in, const int* in_sizes, int n_in,
                              void* d_out, int out_size, void* d_ws, size_t ws_size,
                              hipStream_t stream) {
    const float* x    = (const float*)d_in[0];
    const float* ln1g = (const float*)d_in[1];
    const float* ln1b = (const float*)d_in[2];
    const float* ln2g = (const float*)d_in[3];
    const float* ln2b = (const float*)d_in[4];
    const float* Wq   = (const float*)d_in[5];
    const float* bq   = (const float*)d_in[6];
    const float* Wk   = (const float*)d_in[7];
    const float* bk   = (const float*)d_in[8];
    const float* Wv   = (const float*)d_in[9];
    const float* bv   = (const float*)d_in[10];
    const float* Wo   = (const float*)d_in[11];
    const float* bo   = (const float*)d_in[12];
    const float* Wr   = (const float*)d_in[13];
    const float* br   = (const float*)d_in[14];
    const float* ew1  = (const float*)d_in[15];
    const float* eb1  = (const float*)d_in[16];
    const float* ew2  = (const float*)d_in[17];
    const float* eb2  = (const float*)d_in[18];
    float* out = (float*)d_out;

    char* wsb = (char*)d_ws;
    const size_t MB = 1 << 20;
    unsigned short* ew1T = (unsigned short*)(wsb);               //   0: 64 MB (dead after up)
    unsigned short* eo   = (unsigned short*)(wsb);               //   0: 32 MB = 4 bf16 partials (overlays ew1T)
    unsigned short* ew2T = (unsigned short*)(wsb + 64*MB);       //  64: 64 MB
    unsigned short* mid  = (unsigned short*)(wsb + 128*MB);      // 128: 32 MB [4096][Ff] bf16
    unsigned short* qkvT = (unsigned short*)(wsb + 160*MB);      // 160:  6 MB
    unsigned short* WoT  = (unsigned short*)(wsb + 166*MB);      // 166:  2 MB
    unsigned short* h_bf = (unsigned short*)(wsb + 168*MB);      // 168:  4 MB (dead after QKV)
    unsigned short* qkv  = (unsigned short*)(wsb + 172*MB);      // 172: 12 MB (dead after attn)
    float*          p01  = (float*)         (wsb + 168*MB);      // 168: 16 MB (overlays h_bf+qkv)
    unsigned short* ob   = (unsigned short*)(wsb + 184*MB);      // 184:  4 MB
    unsigned short* h2b  = (unsigned short*)(wsb + 196*MB);      // 196:  4 MB
    float*          w_rt = (float*)         (wsb + 200*MB);
    int*            rows = (int*)           (wsb + 200*MB + 65536);
    int*            counts   = rows + Ee * S;
    int*            offs     = counts + Ee;
    int*            tok2slot = offs + Ee;
    float*          tokw     = (float*)(tok2slot + 2 * S);
    int*            tilemap  = (int*)(tokw + 2 * S);
    int*            ntiles   = tilemap + 40;

    // ---- one-shot weight transpose+convert to bf16 [N][K] ----
    tconv4<<<dim3(16, 16, 4), 256, 0, stream>>>(Wq, Wk, Wv, Wo, qkvT, WoT);
    tconv<<<dim3(64, 16, 8), 256, 0, stream>>>(ew1, ew1T, Dm, Ff);
    tconv<<<dim3(16, 64, 8), 256, 0, stream>>>(ew2, ew2T, Ff, Dm);

    ln_kernel<<<S, 256, 0, stream>>>(x, ln1g, ln1b, h_bf);

    gemm_db<0><<<dim3(24, 16), 256, 0, stream>>>(h_bf, qkvT, bq, bk, bv,
        qkv, S, 3072, Dm);

    attn_mfma<<<dim3(512, 1), 256, 0, stream>>>(qkv, ob);

    gemm_db<1><<<dim3(8, 16, 2), 256, 0, stream>>>(ob, WoT, nullptr, nullptr, nullptr,
        p01, S, Dm, Dm);

    ln2_fused<<<S, 256, 0, stream>>>(x, p01, p01 + (size_t)S * Dm, bo, ln2g, ln2b,
                                     Wr, br, out, h2b, w_rt);
    listbuild_kernel<<<1, 256, 0, stream>>>(w_rt, rows, counts, offs, tok2slot, tokw,
                                            tilemap, ntiles);

    // MoE up: BK=64, 4 blocks/CU — grid 32n x 40mt
    gemm_moe<2><<<dim3(32, 40, 1), 256, 0, stream>>>(h2b, ew1T, eb1,
        mid, rows, counts, offs, tilemap, ntiles, Ff, Dm);

    // MoE down: split-K4, grid 8n x 40mt x 4kc
    gemm_moe<3><<<dim3(8, 40, 4), 256, 0, stream>>>(mid, ew2T, eb2,
        eo, rows, counts, offs, tilemap, ntiles, Dm, Ff);

    combine_kernel<<<S, 256, 0, stream>>>(out, eo, tok2slot, tokw);
}